// Round 13
// baseline (467.852 us; speedup 1.0000x reference)
//
#include <hip/hip_runtime.h>

#define NN 100000
#define EE 1600000
#define IN_F 24
#define HID 128
#define OUT_F 12
#define LBLK 128        // rows per layer-GEMM block

#define NBKT 782        // dst buckets of 128 nodes
#define PA_BLKS 256     // bucket-count / scatter blocks
#define PA_EPB 6250     // EE / PA_BLKS

#define OW_BITS 15
#define OWIN 32768      // out-deg window (64KB packed-u16 LDS)
#define OW_GRP 4        // ceil(NN/OWIN)
#define OW_CPY 32       // copies per window (whist 8.4MB fits ebuf overlay)
#define OW_EPB 50000    // EE / OW_CPY

#define RCAP 2560       // reorder LDS stage capacity (mean 2046, sigma 45 -> 11 sigma)

#define EMB_B 2048
#define PREP_B 264
#define ONORM_B 196     // ceil((NN/2)/256)
#define K1_GRID (PA_BLKS + EMB_B + PREP_B + ONORM_B)   // 2764

typedef unsigned char u8;
typedef unsigned short u16;
typedef unsigned int u32;
typedef unsigned long long u64;

using short8 = __attribute__((ext_vector_type(8))) short;
using f32x4  = __attribute__((ext_vector_type(4))) float;

__device__ __forceinline__ float bf2f(u16 h) {
  return __uint_as_float(((u32)h) << 16);
}
__device__ __forceinline__ u16 f2bf(float f) {
  u32 u = __float_as_uint(f);
  u32 r = (u + 0x7FFFu + ((u >> 16) & 1u)) >> 16;   // RNE
  return (u16)r;
}
__device__ __forceinline__ float inv_sqrt_cnt(int c) {
  if (c < 1) c = 1;
  return 1.0f / sqrtf((float)c);
}

// ---------- out-degree: windowed packed-u16 LDS histograms (no scatter) ----------
__global__ __launch_bounds__(256) void k_odeg(const int* __restrict__ src,
                                              u32* __restrict__ whist) {
  __shared__ u32 hist[OWIN / 2];   // 64KB: u16 pair per u32
  int b = blockIdx.x, t = threadIdx.x;
  int g = b >> 5, sb = b & 31;
  for (int i = t; i < OWIN / 2; i += 256) hist[i] = 0;
  __syncthreads();
  int e0 = sb * OW_EPB;
  for (int e = e0 + t; e < e0 + OW_EPB; e += 256) {
    int s = src[e];
    if ((s >> OW_BITS) == g) {
      int i = s & (OWIN - 1);
      atomicAdd(&hist[i >> 1], (i & 1) ? 0x10000u : 1u);
    }
  }
  __syncthreads();
  u32* out = whist + (size_t)b * (OWIN / 2);
  for (int i = t; i < OWIN / 2; i += 256) out[i] = hist[i];
}

// ---------- K1 sub-bodies ----------
__device__ __forceinline__ void emb_body(int eb, const float* __restrict__ inputs,
                                         const float* __restrict__ W_emb,
                                         const float* __restrict__ b_emb,
                                         u16* __restrict__ harr, float* smemW) {
  int t = threadIdx.x;
  float* Wls = smemW;
  float* bls = smemW + IN_F * HID;
  for (int i = t; i < IN_F * HID; i += 256) Wls[i] = W_emb[i];
  if (t < HID) bls[t] = b_emb[t];
  __syncthreads();
  int c = t & 127;
  int sub = t >> 7;
  for (int node = eb * 2 + sub; node < NN; node += EMB_B * 2) {
    const float* xr = inputs + (size_t)node * IN_F;
    float acc = bls[c];
    #pragma unroll
    for (int k = 0; k < IN_F; ++k) acc = fmaf(xr[k], Wls[k * HID + c], acc);
    harr[(size_t)node * HID + c] = f2bf(acc);
  }
}

__device__ __forceinline__ void prep_body(int pb,
    const float* __restrict__ Ws1, const float* __restrict__ W1m,
    const float* __restrict__ Ws2, const float* __restrict__ W2m,
    const float* __restrict__ Wfc,
    u16* __restrict__ WT1, u16* __restrict__ WT2, u16* __restrict__ WfcT) {
  int idx = pb * 256 + (int)threadIdx.x;
  if (idx < 65536) {
    int layer = idx >> 15;
    int rem = idx & 32767;
    int n = rem >> 8, k = rem & 255;
    const float* A = layer ? Ws2 : Ws1;
    const float* B = layer ? W2m : W1m;
    float v = (k < HID) ? A[(size_t)k * HID + n] : B[(size_t)(k - HID) * HID + n];
    (layer ? WT2 : WT1)[(size_t)n * 256 + k] = f2bf(v);
  } else if (idx < 65536 + 2048) {
    int j = idx - 65536;
    int n = j >> 7, k = j & 127;
    WfcT[(size_t)n * 128 + k] = f2bf(n < OUT_F ? Wfc[(size_t)k * OUT_F + n] : 0.f);
  }
}

__device__ __forceinline__ void onorm_body(int ob, const u32* __restrict__ whist,
                                           float* __restrict__ out_norm) {
  int i = ob * 256 + (int)threadIdx.x;   // packed node pair
  if (i >= NN / 2) return;
  int n0 = 2 * i;
  int g = n0 >> OW_BITS;
  int pi = (n0 & (OWIN - 1)) >> 1;
  const u32* base = whist + (size_t)(g * OW_CPY) * (OWIN / 2) + pi;
  u32 s = 0;
  #pragma unroll 8
  for (int c = 0; c < OW_CPY; ++c) s += base[(size_t)c * (OWIN / 2)];
  out_norm[n0]     = inv_sqrt_cnt((int)(s & 0xFFFFu));
  out_norm[n0 + 1] = inv_sqrt_cnt((int)(s >> 16));
}

// K1: fused [dst bucket-count | emb | weight prep | out-norm merge]; zeroes ticket.
__global__ __launch_bounds__(256) void k1(
    const int* __restrict__ dst, u32* __restrict__ histgD,
    const float* __restrict__ inputs, const float* __restrict__ W_emb,
    const float* __restrict__ b_emb, u16* __restrict__ harr,
    const float* __restrict__ Ws1, const float* __restrict__ W1m,
    const float* __restrict__ Ws2, const float* __restrict__ W2m,
    const float* __restrict__ Wfc,
    u16* __restrict__ WT1, u16* __restrict__ WT2, u16* __restrict__ WfcT,
    const u32* __restrict__ whist, float* __restrict__ out_norm,
    u32* __restrict__ ticket) {
  __shared__ __align__(16) char sm[13312];
  int b = blockIdx.x, t = threadIdx.x;
  if (b == 0 && t == 0) *ticket = 0;
  if (b < PA_BLKS) {
    u32* histD = (u32*)sm;
    for (int i = t; i < 1024; i += 256) histD[i] = 0;
    __syncthreads();
    int e0 = b * PA_EPB;
    for (int e = e0 + t; e < e0 + PA_EPB; e += 256)
      atomicAdd(&histD[dst[e] >> 7], 1u);
    __syncthreads();
    for (int i = t; i < 1024; i += 256) histgD[(size_t)b * 1024 + i] = histD[i];
  } else if (b < PA_BLKS + EMB_B) {
    emb_body(b - PA_BLKS, inputs, W_emb, b_emb, harr, (float*)sm);
  } else if (b < PA_BLKS + EMB_B + PREP_B) {
    prep_body(b - PA_BLKS - EMB_B, Ws1, W1m, Ws2, W2m, Wfc, WT1, WT2, WfcT);
  } else {
    onorm_body(b - PA_BLKS - EMB_B - PREP_B, whist, out_norm);
  }
}

// scan12: per-bucket exclusive scan over the 256 count blocks (in-place) + total;
// the LAST block (device-scope ticket) then scans totals -> estart[0..NBKT].
__global__ __launch_bounds__(256) void k_scan12(u32* __restrict__ histgD,
                                                u32* __restrict__ totalsD,
                                                u32* __restrict__ estartD,
                                                u32* __restrict__ ticket) {
  __shared__ u32 s[256];
  __shared__ u32 lastflag;
  int k = blockIdx.x, t = threadIdx.x;
  u32 v = histgD[(size_t)t * 1024 + k];
  s[t] = v;
  __syncthreads();
  for (int off = 1; off < 256; off <<= 1) {
    u32 a = (t >= off) ? s[t - off] : 0;
    __syncthreads();
    s[t] += a;
    __syncthreads();
  }
  histgD[(size_t)t * 1024 + k] = s[t] - v;   // exclusive
  if (t == 255) totalsD[k] = s[255];
  __threadfence();
  if (t == 0) {
    u32 old = atomicAdd(ticket, 1u);
    lastflag = (old == NBKT - 1) ? 1u : 0u;
  }
  __syncthreads();
  if (lastflag) {
    __threadfence();   // acquire: make all blocks' totalsD stores visible
    u32 loc[4];
    u32 tot = 0;
    #pragma unroll
    for (int q = 0; q < 4; ++q) {
      int idx = t * 4 + q;
      loc[q] = (idx < NBKT) ? totalsD[idx] : 0;
      tot += loc[q];
    }
    s[t] = tot;
    __syncthreads();
    for (int off = 1; off < 256; off <<= 1) {
      u32 a = (t >= off) ? s[t - off] : 0;
      __syncthreads();
      s[t] += a;
      __syncthreads();
    }
    u32 base = s[t] - tot;
    #pragma unroll
    for (int q = 0; q < 4; ++q) {
      int idx = t * 4 + q;
      if (idx <= NBKT) estartD[idx] = base;
      base += loc[q];
    }
    if (t == 0) *ticket = 0;
  }
}

// passB: scatter u64 edge records to bucket order via LDS cursors.
__global__ __launch_bounds__(256) void k_passb(
    const int* __restrict__ src, const int* __restrict__ dst,
    const float* __restrict__ e_w,
    const u32* __restrict__ histgD, const u32* __restrict__ estartD,
    u64* __restrict__ ebuf) {
  __shared__ u32 cur[1024];
  int pb = blockIdx.x, t = threadIdx.x;
  for (int i = t; i < 1024; i += 256)
    cur[i] = ((i < NBKT) ? estartD[i] : 0u) + histgD[(size_t)pb * 1024 + i];
  __syncthreads();
  int e0 = pb * PA_EPB;
  for (int e = e0 + t; e < e0 + PA_EPB; e += 256) {
    int s = src[e], d = dst[e];
    u32 hi = (u32)s | (((u32)(d & 127)) << 17);
    u64 rec = ((u64)hi << 32) | (u64)__float_as_uint(e_w[e]);
    u32 pos = atomicAdd(&cur[d >> 7], 1u);   // LDS atomic
    ebuf[pos] = rec;
  }
}

// reorder: within-bucket counting sort IN PLACE via LDS staging.
__global__ __launch_bounds__(256) void k_reorder(
    u64* __restrict__ ebuf, const u32* __restrict__ estart,
    int* __restrict__ row_start, float* __restrict__ in_norm) {
  __shared__ u64 stage[RCAP];
  __shared__ u32 cnt[128], pfx[128], cur[128];
  int k = blockIdx.x, t = threadIdx.x;
  if (t < 128) cnt[t] = 0;
  __syncthreads();
  int e0 = (int)estart[k], e1 = (int)estart[k + 1];
  int n = e1 - e0; if (n > RCAP) n = RCAP;   // 11-sigma impossible
  for (int i = t; i < n; i += 256) {
    u64 v = ebuf[e0 + i];
    stage[i] = v;
    atomicAdd(&cnt[(u32)(v >> 49) & 127], 1u);
  }
  __syncthreads();
  if (t < 128) pfx[t] = cnt[t];
  __syncthreads();
  for (int off = 1; off < 128; off <<= 1) {
    u32 v = (t < 128 && t >= off) ? pfx[t - off] : 0;
    __syncthreads();
    if (t < 128) pfx[t] += v;
    __syncthreads();
  }
  if (t < 128) {
    u32 start = (u32)e0 + pfx[t] - cnt[t];
    cur[t] = start;
    int node = k * 128 + t;
    if (node < NN) {
      row_start[node] = (int)start;
      in_norm[node] = inv_sqrt_cnt((int)cnt[t]);
    }
  }
  if (k == NBKT - 1 && t == 0) row_start[NN] = e1;
  __syncthreads();
  for (int i = t; i < n; i += 256) {
    u64 v = stage[i];
    u32 pos = atomicAdd(&cur[(u32)(v >> 49) & 127], 1u);
    ebuf[pos] = v;
  }
}

// agg (round-10 proven form + NT hints): streaming ebuf reads and aggr writes
// bypass L2 replacement so gather lines stay resident.
__global__ __launch_bounds__(256) void k_agg(const u16* __restrict__ harr,
                                             const int* __restrict__ row_start,
                                             const float* __restrict__ in_norm,
                                             const float* __restrict__ out_norm,
                                             const u64* __restrict__ ebuf,
                                             u16* __restrict__ aggr) {
  int t = threadIdx.x;
  int node = blockIdx.x * 8 + (t >> 5);
  if (node >= NN) return;
  int lane = t & 31;
  int s0 = row_start[node], s1 = row_start[node + 1];
  float ax = 0.f, ay = 0.f, az = 0.f, aw = 0.f;
  for (int i0 = s0; i0 < s1; i0 += 32) {
    u32 pk2 = 0;
    if (i0 + lane < s1) {
      u64 rec = __builtin_nontemporal_load(&ebuf[i0 + lane]);
      u32 sv = (u32)(rec >> 32) & 0x1FFFF;
      float w = __uint_as_float((u32)rec) * out_norm[sv];
      pk2 = (((u32)f2bf(w)) << 17) | sv;
    }
    int m = s1 - i0; if (m > 32) m = 32;
    int j = 0;
    for (; j + 4 <= m; j += 4) {
      u32 p0 = __shfl(pk2, j,     32);
      u32 p1 = __shfl(pk2, j + 1, 32);
      u32 p2 = __shfl(pk2, j + 2, 32);
      u32 p3 = __shfl(pk2, j + 3, 32);
      ushort4 h0 = *(const ushort4*)(harr + (size_t)(p0 & 0x1FFFF) * HID + lane * 4);
      ushort4 h1 = *(const ushort4*)(harr + (size_t)(p1 & 0x1FFFF) * HID + lane * 4);
      ushort4 h2 = *(const ushort4*)(harr + (size_t)(p2 & 0x1FFFF) * HID + lane * 4);
      ushort4 h3 = *(const ushort4*)(harr + (size_t)(p3 & 0x1FFFF) * HID + lane * 4);
      float w0 = bf2f((u16)(p0 >> 17));
      float w1 = bf2f((u16)(p1 >> 17));
      float w2 = bf2f((u16)(p2 >> 17));
      float w3 = bf2f((u16)(p3 >> 17));
      ax = fmaf(w0, bf2f(h0.x), ax); ay = fmaf(w0, bf2f(h0.y), ay);
      az = fmaf(w0, bf2f(h0.z), az); aw = fmaf(w0, bf2f(h0.w), aw);
      ax = fmaf(w1, bf2f(h1.x), ax); ay = fmaf(w1, bf2f(h1.y), ay);
      az = fmaf(w1, bf2f(h1.z), az); aw = fmaf(w1, bf2f(h1.w), aw);
      ax = fmaf(w2, bf2f(h2.x), ax); ay = fmaf(w2, bf2f(h2.y), ay);
      az = fmaf(w2, bf2f(h2.z), az); aw = fmaf(w2, bf2f(h2.w), aw);
      ax = fmaf(w3, bf2f(h3.x), ax); ay = fmaf(w3, bf2f(h3.y), ay);
      az = fmaf(w3, bf2f(h3.z), az); aw = fmaf(w3, bf2f(h3.w), aw);
    }
    for (; j < m; ++j) {
      u32 p = __shfl(pk2, j, 32);
      float w = bf2f((u16)(p >> 17));
      ushort4 hv = *(const ushort4*)(harr + (size_t)(p & 0x1FFFF) * HID + lane * 4);
      ax = fmaf(w, bf2f(hv.x), ax); ay = fmaf(w, bf2f(hv.y), ay);
      az = fmaf(w, bf2f(hv.z), az); aw = fmaf(w, bf2f(hv.w), aw);
    }
  }
  float inn = in_norm[node];
  u64 pk = (u64)(((u32)f2bf(ay * inn) << 16) | (u32)f2bf(ax * inn))
         | ((u64)(((u32)f2bf(aw * inn) << 16) | (u32)f2bf(az * inn)) << 32);
  __builtin_nontemporal_store(pk, (u64*)(aggr + (size_t)node * HID + lane * 4));
}

// ---------- MFMA layer GEMM (128x128, K=256), optional fused FC ----------
template<int FC>
__global__ __launch_bounds__(512) void k_layer(u16* __restrict__ harr,
    const u16* __restrict__ aggr,
    const u16* __restrict__ WT, const float* __restrict__ bias,
    const float* __restrict__ in_norm,
    const u16* __restrict__ WfcT, const float* __restrict__ b_fc,
    float* __restrict__ out) {
  __shared__ char smem[135168];
  const int t = threadIdx.x;
  const int r0 = blockIdx.x * LBLK;

  #pragma unroll
  for (int i = 0; i < 4; ++i) {      // stage X h-half (32KB)
    int boff = i * 8192 + t * 16;
    int row = boff >> 8, col = boff & 255;
    uint4 v = *(const uint4*)(harr + (size_t)(r0 + row) * HID + (col >> 1));
    *(uint4*)(smem + row * 512 + (col ^ ((row & 7) << 4))) = v;
  }
  #pragma unroll
  for (int i = 0; i < 4; ++i) {      // stage X agg-half (32KB)
    int boff = i * 8192 + t * 16;
    int row = boff >> 8, col = boff & 255;
    uint4 v = *(const uint4*)(aggr + (size_t)(r0 + row) * HID + (col >> 1));
    *(uint4*)(smem + row * 512 + (256 + (col ^ ((row & 7) << 4)))) = v;
  }
  #pragma unroll
  for (int i = 0; i < 8; ++i) {      // stage W (64KB)
    int boff = i * 8192 + t * 16;
    int row = boff >> 9, col = boff & 511;
    uint4 v = *(const uint4*)(WT + (size_t)row * 256 + (col >> 1));
    *(uint4*)(smem + 65536 + row * 512 + (col ^ ((row & 7) << 4))) = v;
  }
  if (FC && t < 256) {               // stage WfcT (4KB)
    int row = t >> 4, col = (t & 15) * 16;
    uint4 v = *(const uint4*)(WfcT + (size_t)row * 128 + (col >> 1));
    *(uint4*)(smem + 131072 + row * 256 + (col ^ ((row & 7) << 4))) = v;
  }
  __syncthreads();

  const int lane = t & 63, w = t >> 6;
  const int l15 = lane & 15, lhi = lane >> 4;

  f32x4 acc[8];
  #pragma unroll
  for (int nf = 0; nf < 8; ++nf) acc[nf] = (f32x4){0.f, 0.f, 0.f, 0.f};

  const int arow = w * 16 + l15;
  const char* pa = smem + arow * 512;
  const int aswz = (arow & 7) << 4;
  #pragma unroll
  for (int ks = 0; ks < 8; ++ks) {
    int kb = ks * 64 + (lhi << 4);
    short8 a = *(const short8*)(pa + (kb ^ aswz));
    #pragma unroll
    for (int nf = 0; nf < 8; ++nf) {
      int brow = nf * 16 + l15;
      short8 bf = *(const short8*)(smem + 65536 + brow * 512 + (kb ^ ((brow & 7) << 4)));
      acc[nf] = __builtin_amdgcn_mfma_f32_16x16x32_bf16(a, bf, acc[nf], 0, 0, 0);
    }
  }

  float bcol[8];
  #pragma unroll
  for (int nf = 0; nf < 8; ++nf) bcol[nf] = bias[nf * 16 + l15];

  if (!FC) {
    #pragma unroll
    for (int r = 0; r < 4; ++r) {
      int grow = r0 + w * 16 + (lhi << 2) + r;
      if (grow < NN) {
        float inn = in_norm[grow];
        #pragma unroll
        for (int nf = 0; nf < 8; ++nf) {
          float v = acc[nf][r] + inn * bcol[nf];
          harr[(size_t)grow * HID + nf * 16 + l15] = f2bf(fmaxf(v, 0.f));
        }
      }
    }
  } else {
    __syncthreads();   // h2 overlays X rows: wait until all waves done reading X
    #pragma unroll
    for (int r = 0; r < 4; ++r) {
      int lrow = w * 16 + (lhi << 2) + r;
      int grow = r0 + lrow;
      float inn = (grow < NN) ? in_norm[grow] : 0.f;
      #pragma unroll
      for (int nf = 0; nf < 8; ++nf) {
        int col = nf * 16 + l15;
        float v = fmaxf(acc[nf][r] + inn * bcol[nf], 0.f);
        *(u16*)(smem + lrow * 256 + ((col * 2) ^ ((lrow & 7) << 4))) = f2bf(v);
      }
    }
    __syncthreads();
    f32x4 a2 = (f32x4){0.f, 0.f, 0.f, 0.f};
    const char* pa2 = smem + (w * 16 + l15) * 256;
    const int as2 = (l15 & 7) << 4;
    #pragma unroll
    for (int ks = 0; ks < 4; ++ks) {
      int kb = ks * 64 + (lhi << 4);
      short8 a = *(const short8*)(pa2 + (kb ^ as2));
      short8 bf = *(const short8*)(smem + 131072 + l15 * 256 + (kb ^ as2));
      a2 = __builtin_amdgcn_mfma_f32_16x16x32_bf16(a, bf, a2, 0, 0, 0);
    }
    if (l15 < OUT_F) {
      float bo = b_fc[l15];
      #pragma unroll
      for (int r = 0; r < 4; ++r) {
        int grow = r0 + w * 16 + (lhi << 2) + r;
        if (grow < NN) out[(size_t)grow * OUT_F + l15] = a2[r] + bo;
      }
    }
  }
}

extern "C" void kernel_launch(void* const* d_in, const int* in_sizes, int n_in,
                              void* d_out, int out_size, void* d_ws, size_t ws_size,
                              hipStream_t stream) {
  (void)in_sizes; (void)n_in; (void)out_size;
  const float* inputs  = (const float*)d_in[0];
  const int*   src     = (const int*)d_in[1];
  const int*   dst     = (const int*)d_in[2];
  const float* e_w     = (const float*)d_in[3];
  const float* W_emb   = (const float*)d_in[6];
  const float* b_emb   = (const float*)d_in[7];
  const float* W_self1 = (const float*)d_in[8];
  const float* W1      = (const float*)d_in[9];
  const float* b1      = (const float*)d_in[10];
  const float* W_self2 = (const float*)d_in[11];
  const float* W2      = (const float*)d_in[12];
  const float* b2      = (const float*)d_in[13];
  const float* W_fc    = (const float*)d_in[14];
  const float* b_fc    = (const float*)d_in[15];
  float* out = (float*)d_out;

  // layout (66.4 MB, < proven 72.2 MB) — round-10 layout:
  // [histgD 1M | totalsD 4K | estartD 4K (ticket = estartD[1023]) | out_norm
  //  | in_norm | row_start | ebuf u64 EE 12.8M | harr 25.6M | aggr 25.6M | WTs]
  // whist (u32, 128*16384 = 8.4MB) overlays ebuf ONLY (consumed by k1's onorm
  // before k_passb writes ebuf; no harr conflict).
  u32* histgD      = (u32*)d_ws;
  u32* totalsD     = histgD + (size_t)PA_BLKS * 1024;
  u32* estartD     = totalsD + 1024;
  u32* ticket      = estartD + 1023;     // estartD uses [0..NBKT]=783 slots
  float* out_norm  = (float*)(estartD + 1024);
  float* in_norm   = out_norm + NN;
  int* row_start   = (int*)(in_norm + NN);
  u64* ebuf        = (u64*)(row_start + NN + 4);
  u16* harr        = (u16*)(ebuf + EE);
  u16* aggr        = harr + (size_t)NN * HID;
  u16* WT1         = aggr + (size_t)NN * HID;
  u16* WT2         = WT1 + 32768;
  u16* WfcT        = WT2 + 32768;
  u32* whist       = (u32*)ebuf;         // 8.4MB overlay inside ebuf (12.8MB)

  const size_t NEED = (size_t)PA_BLKS * 1024 * 4 + 2048 * 4 + (size_t)(3 * NN + 4) * 4
                      + (size_t)EE * 8 + (size_t)NN * HID * 4 + (2 * 32768 + 2048) * 2;
  if (ws_size < NEED) return;

  hipLaunchKernelGGL(k_odeg, dim3(OW_GRP * OW_CPY), dim3(256), 0, stream, src, whist);
  hipLaunchKernelGGL(k1, dim3(K1_GRID), dim3(256), 0, stream,
                     dst, histgD, inputs, W_emb, b_emb, harr,
                     W_self1, W1, W_self2, W2, W_fc, WT1, WT2, WfcT,
                     whist, out_norm, ticket);
  hipLaunchKernelGGL(k_scan12, dim3(NBKT), dim3(256), 0, stream,
                     histgD, totalsD, estartD, ticket);
  hipLaunchKernelGGL(k_passb, dim3(PA_BLKS), dim3(256), 0, stream,
                     src, dst, e_w, histgD, estartD, ebuf);
  hipLaunchKernelGGL(k_reorder, dim3(NBKT), dim3(256), 0, stream,
                     ebuf, estartD, row_start, in_norm);
  // layer 1
  hipLaunchKernelGGL(k_agg, dim3((NN + 7) / 8), dim3(256), 0, stream,
                     harr, row_start, in_norm, out_norm, ebuf, aggr);
  hipLaunchKernelGGL(k_layer<0>, dim3((NN + LBLK - 1) / LBLK), dim3(512), 0, stream,
                     harr, aggr, WT1, b1, in_norm, WfcT, b_fc, out);
  // layer 2 + fused FC
  hipLaunchKernelGGL(k_agg, dim3((NN + 7) / 8), dim3(256), 0, stream,
                     harr, row_start, in_norm, out_norm, ebuf, aggr);
  hipLaunchKernelGGL(k_layer<1>, dim3((NN + LBLK - 1) / LBLK), dim3(512), 0, stream,
                     harr, aggr, WT2, b2, in_norm, WfcT, b_fc, out);
}

// Round 14
// 372.648 us; speedup vs baseline: 1.2555x; 1.2555x over previous
//
#include <hip/hip_runtime.h>

#define NN 100000
#define EE 1600000
#define IN_F 24
#define HID 128
#define OUT_F 12
#define LBLK 128        // rows per layer-GEMM block

#define NBKT 782        // dst buckets of 128 nodes
#define PA_BLKS 256     // bucket-count / scatter blocks
#define PA_EPB 6250     // EE / PA_BLKS

#define OW_BITS 15
#define OWIN 32768      // out-deg window (64KB packed-u16 LDS)
#define OW_GRP 4        // ceil(NN/OWIN)
#define OW_CPY 32       // copies per window (whist 8.4MB fits ebuf overlay)
#define OW_EPB 50000    // EE / OW_CPY

#define RCAP 2560       // reorder LDS stage capacity (mean 2046, sigma 45 -> 11 sigma)

#define EMB_B 2048
#define PREP_B 264
#define ONORM_B 196     // ceil((NN/2)/256)
#define K1_GRID (PA_BLKS + EMB_B + PREP_B + ONORM_B)   // 2764

typedef unsigned char u8;
typedef unsigned short u16;
typedef unsigned int u32;
typedef unsigned long long u64;

using short8 = __attribute__((ext_vector_type(8))) short;
using f32x4  = __attribute__((ext_vector_type(4))) float;

__device__ __forceinline__ float bf2f(u16 h) {
  return __uint_as_float(((u32)h) << 16);
}
__device__ __forceinline__ u16 f2bf(float f) {
  u32 u = __float_as_uint(f);
  u32 r = (u + 0x7FFFu + ((u >> 16) & 1u)) >> 16;   // RNE
  return (u16)r;
}
__device__ __forceinline__ float inv_sqrt_cnt(int c) {
  if (c < 1) c = 1;
  return 1.0f / sqrtf((float)c);
}

// ---------- out-degree: windowed packed-u16 LDS histograms (no scatter) ----------
__global__ __launch_bounds__(256) void k_odeg(const int* __restrict__ src,
                                              u32* __restrict__ whist) {
  __shared__ u32 hist[OWIN / 2];   // 64KB: u16 pair per u32
  int b = blockIdx.x, t = threadIdx.x;
  int g = b >> 5, sb = b & 31;
  for (int i = t; i < OWIN / 2; i += 256) hist[i] = 0;
  __syncthreads();
  int e0 = sb * OW_EPB;
  for (int e = e0 + t; e < e0 + OW_EPB; e += 256) {
    int s = src[e];
    if ((s >> OW_BITS) == g) {
      int i = s & (OWIN - 1);
      atomicAdd(&hist[i >> 1], (i & 1) ? 0x10000u : 1u);
    }
  }
  __syncthreads();
  u32* out = whist + (size_t)b * (OWIN / 2);
  for (int i = t; i < OWIN / 2; i += 256) out[i] = hist[i];
}

// ---------- K1 sub-bodies ----------
__device__ __forceinline__ void emb_body(int eb, const float* __restrict__ inputs,
                                         const float* __restrict__ W_emb,
                                         const float* __restrict__ b_emb,
                                         u16* __restrict__ harr, float* smemW) {
  int t = threadIdx.x;
  float* Wls = smemW;
  float* bls = smemW + IN_F * HID;
  for (int i = t; i < IN_F * HID; i += 256) Wls[i] = W_emb[i];
  if (t < HID) bls[t] = b_emb[t];
  __syncthreads();
  int c = t & 127;
  int sub = t >> 7;
  for (int node = eb * 2 + sub; node < NN; node += EMB_B * 2) {
    const float* xr = inputs + (size_t)node * IN_F;
    float acc = bls[c];
    #pragma unroll
    for (int k = 0; k < IN_F; ++k) acc = fmaf(xr[k], Wls[k * HID + c], acc);
    harr[(size_t)node * HID + c] = f2bf(acc);
  }
}

__device__ __forceinline__ void prep_body(int pb,
    const float* __restrict__ Ws1, const float* __restrict__ W1m,
    const float* __restrict__ Ws2, const float* __restrict__ W2m,
    const float* __restrict__ Wfc,
    u16* __restrict__ WT1, u16* __restrict__ WT2, u16* __restrict__ WfcT) {
  int idx = pb * 256 + (int)threadIdx.x;
  if (idx < 65536) {
    int layer = idx >> 15;
    int rem = idx & 32767;
    int n = rem >> 8, k = rem & 255;
    const float* A = layer ? Ws2 : Ws1;
    const float* B = layer ? W2m : W1m;
    float v = (k < HID) ? A[(size_t)k * HID + n] : B[(size_t)(k - HID) * HID + n];
    (layer ? WT2 : WT1)[(size_t)n * 256 + k] = f2bf(v);
  } else if (idx < 65536 + 2048) {
    int j = idx - 65536;
    int n = j >> 7, k = j & 127;
    WfcT[(size_t)n * 128 + k] = f2bf(n < OUT_F ? Wfc[(size_t)k * OUT_F + n] : 0.f);
  }
}

__device__ __forceinline__ void onorm_body(int ob, const u32* __restrict__ whist,
                                           float* __restrict__ out_norm) {
  int i = ob * 256 + (int)threadIdx.x;   // packed node pair
  if (i >= NN / 2) return;
  int n0 = 2 * i;
  int g = n0 >> OW_BITS;
  int pi = (n0 & (OWIN - 1)) >> 1;
  const u32* base = whist + (size_t)(g * OW_CPY) * (OWIN / 2) + pi;
  u32 s = 0;
  #pragma unroll 8
  for (int c = 0; c < OW_CPY; ++c) s += base[(size_t)c * (OWIN / 2)];
  out_norm[n0]     = inv_sqrt_cnt((int)(s & 0xFFFFu));
  out_norm[n0 + 1] = inv_sqrt_cnt((int)(s >> 16));
}

// K1: fused [dst bucket-count | emb | weight prep | out-norm merge]
__global__ __launch_bounds__(256) void k1(
    const int* __restrict__ dst, u32* __restrict__ histgD,
    const float* __restrict__ inputs, const float* __restrict__ W_emb,
    const float* __restrict__ b_emb, u16* __restrict__ harr,
    const float* __restrict__ Ws1, const float* __restrict__ W1m,
    const float* __restrict__ Ws2, const float* __restrict__ W2m,
    const float* __restrict__ Wfc,
    u16* __restrict__ WT1, u16* __restrict__ WT2, u16* __restrict__ WfcT,
    const u32* __restrict__ whist, float* __restrict__ out_norm) {
  __shared__ __align__(16) char sm[13312];
  int b = blockIdx.x, t = threadIdx.x;
  if (b < PA_BLKS) {
    u32* histD = (u32*)sm;
    for (int i = t; i < 1024; i += 256) histD[i] = 0;
    __syncthreads();
    int e0 = b * PA_EPB;
    for (int e = e0 + t; e < e0 + PA_EPB; e += 256)
      atomicAdd(&histD[dst[e] >> 7], 1u);
    __syncthreads();
    for (int i = t; i < 1024; i += 256) histgD[(size_t)b * 1024 + i] = histD[i];
  } else if (b < PA_BLKS + EMB_B) {
    emb_body(b - PA_BLKS, inputs, W_emb, b_emb, harr, (float*)sm);
  } else if (b < PA_BLKS + EMB_B + PREP_B) {
    prep_body(b - PA_BLKS - EMB_B, Ws1, W1m, Ws2, W2m, Wfc, WT1, WT2, WfcT);
  } else {
    onorm_body(b - PA_BLKS - EMB_B - PREP_B, whist, out_norm);
  }
}

// scan1: per bucket k, exclusive scan over the 256 count blocks (in-place) + total
__global__ __launch_bounds__(256) void k_scan1(u32* __restrict__ histgD,
                                               u32* __restrict__ totalsD) {
  __shared__ u32 s[256];
  int k = blockIdx.x, t = threadIdx.x;
  u32 v = histgD[(size_t)t * 1024 + k];
  s[t] = v;
  __syncthreads();
  for (int off = 1; off < 256; off <<= 1) {
    u32 a = (t >= off) ? s[t - off] : 0;
    __syncthreads();
    s[t] += a;
    __syncthreads();
  }
  histgD[(size_t)t * 1024 + k] = s[t] - v;   // exclusive
  if (t == 255) totalsD[k] = s[255];
}

// scan2: exclusive scan over bucket totals -> estart[0..NBKT]
__global__ __launch_bounds__(1024) void k_scan2(const u32* __restrict__ totalsD,
                                                u32* __restrict__ estartD) {
  __shared__ u32 s[1024];
  int t = threadIdx.x;
  u32 v = (t < NBKT) ? totalsD[t] : 0;
  s[t] = v;
  __syncthreads();
  for (int off = 1; off < 1024; off <<= 1) {
    u32 a = (t >= off) ? s[t - off] : 0;
    __syncthreads();
    s[t] += a;
    __syncthreads();
  }
  if (t < NBKT) estartD[t] = s[t] - v;
  if (t == NBKT - 1) estartD[NBKT] = s[t];
}

// passB: scatter u64 edge records to bucket order via LDS cursors.
__global__ __launch_bounds__(256) void k_passb(
    const int* __restrict__ src, const int* __restrict__ dst,
    const float* __restrict__ e_w,
    const u32* __restrict__ histgD, const u32* __restrict__ estartD,
    u64* __restrict__ ebuf) {
  __shared__ u32 cur[1024];
  int pb = blockIdx.x, t = threadIdx.x;
  for (int i = t; i < 1024; i += 256)
    cur[i] = ((i < NBKT) ? estartD[i] : 0u) + histgD[(size_t)pb * 1024 + i];
  __syncthreads();
  int e0 = pb * PA_EPB;
  for (int e = e0 + t; e < e0 + PA_EPB; e += 256) {
    int s = src[e], d = dst[e];
    u32 hi = (u32)s | (((u32)(d & 127)) << 17);
    u64 rec = ((u64)hi << 32) | (u64)__float_as_uint(e_w[e]);
    u32 pos = atomicAdd(&cur[d >> 7], 1u);   // LDS atomic
    ebuf[pos] = rec;
  }
}

// reorder: within-bucket counting sort IN PLACE via LDS staging.
__global__ __launch_bounds__(256) void k_reorder(
    u64* __restrict__ ebuf, const u32* __restrict__ estart,
    int* __restrict__ row_start, float* __restrict__ in_norm) {
  __shared__ u64 stage[RCAP];
  __shared__ u32 cnt[128], pfx[128], cur[128];
  int k = blockIdx.x, t = threadIdx.x;
  if (t < 128) cnt[t] = 0;
  __syncthreads();
  int e0 = (int)estart[k], e1 = (int)estart[k + 1];
  int n = e1 - e0; if (n > RCAP) n = RCAP;   // 11-sigma impossible
  for (int i = t; i < n; i += 256) {
    u64 v = ebuf[e0 + i];
    stage[i] = v;
    atomicAdd(&cnt[(u32)(v >> 49) & 127], 1u);
  }
  __syncthreads();
  if (t < 128) pfx[t] = cnt[t];
  __syncthreads();
  for (int off = 1; off < 128; off <<= 1) {
    u32 v = (t < 128 && t >= off) ? pfx[t - off] : 0;
    __syncthreads();
    if (t < 128) pfx[t] += v;
    __syncthreads();
  }
  if (t < 128) {
    u32 start = (u32)e0 + pfx[t] - cnt[t];
    cur[t] = start;
    int node = k * 128 + t;
    if (node < NN) {
      row_start[node] = (int)start;
      in_norm[node] = inv_sqrt_cnt((int)cnt[t]);
    }
  }
  if (k == NBKT - 1 && t == 0) row_start[NN] = e1;
  __syncthreads();
  for (int i = t; i < n; i += 256) {
    u64 v = stage[i];
    u32 pos = atomicAdd(&cur[(u32)(v >> 49) & 127], 1u);
    ebuf[pos] = v;
  }
}

// agg (round-10 proven form): 4-deep MLP gather from compact harr.
__global__ __launch_bounds__(256) void k_agg(const u16* __restrict__ harr,
                                             const int* __restrict__ row_start,
                                             const float* __restrict__ in_norm,
                                             const float* __restrict__ out_norm,
                                             const u64* __restrict__ ebuf,
                                             u16* __restrict__ aggr) {
  int t = threadIdx.x;
  int node = blockIdx.x * 8 + (t >> 5);
  if (node >= NN) return;
  int lane = t & 31;
  int s0 = row_start[node], s1 = row_start[node + 1];
  float ax = 0.f, ay = 0.f, az = 0.f, aw = 0.f;
  for (int i0 = s0; i0 < s1; i0 += 32) {
    u32 pk2 = 0;
    if (i0 + lane < s1) {
      u64 rec = ebuf[i0 + lane];
      u32 sv = (u32)(rec >> 32) & 0x1FFFF;
      float w = __uint_as_float((u32)rec) * out_norm[sv];
      pk2 = (((u32)f2bf(w)) << 17) | sv;
    }
    int m = s1 - i0; if (m > 32) m = 32;
    int j = 0;
    for (; j + 4 <= m; j += 4) {
      u32 p0 = __shfl(pk2, j,     32);
      u32 p1 = __shfl(pk2, j + 1, 32);
      u32 p2 = __shfl(pk2, j + 2, 32);
      u32 p3 = __shfl(pk2, j + 3, 32);
      ushort4 h0 = *(const ushort4*)(harr + (size_t)(p0 & 0x1FFFF) * HID + lane * 4);
      ushort4 h1 = *(const ushort4*)(harr + (size_t)(p1 & 0x1FFFF) * HID + lane * 4);
      ushort4 h2 = *(const ushort4*)(harr + (size_t)(p2 & 0x1FFFF) * HID + lane * 4);
      ushort4 h3 = *(const ushort4*)(harr + (size_t)(p3 & 0x1FFFF) * HID + lane * 4);
      float w0 = bf2f((u16)(p0 >> 17));
      float w1 = bf2f((u16)(p1 >> 17));
      float w2 = bf2f((u16)(p2 >> 17));
      float w3 = bf2f((u16)(p3 >> 17));
      ax = fmaf(w0, bf2f(h0.x), ax); ay = fmaf(w0, bf2f(h0.y), ay);
      az = fmaf(w0, bf2f(h0.z), az); aw = fmaf(w0, bf2f(h0.w), aw);
      ax = fmaf(w1, bf2f(h1.x), ax); ay = fmaf(w1, bf2f(h1.y), ay);
      az = fmaf(w1, bf2f(h1.z), az); aw = fmaf(w1, bf2f(h1.w), aw);
      ax = fmaf(w2, bf2f(h2.x), ax); ay = fmaf(w2, bf2f(h2.y), ay);
      az = fmaf(w2, bf2f(h2.z), az); aw = fmaf(w2, bf2f(h2.w), aw);
      ax = fmaf(w3, bf2f(h3.x), ax); ay = fmaf(w3, bf2f(h3.y), ay);
      az = fmaf(w3, bf2f(h3.z), az); aw = fmaf(w3, bf2f(h3.w), aw);
    }
    for (; j < m; ++j) {
      u32 p = __shfl(pk2, j, 32);
      float w = bf2f((u16)(p >> 17));
      ushort4 hv = *(const ushort4*)(harr + (size_t)(p & 0x1FFFF) * HID + lane * 4);
      ax = fmaf(w, bf2f(hv.x), ax); ay = fmaf(w, bf2f(hv.y), ay);
      az = fmaf(w, bf2f(hv.z), az); aw = fmaf(w, bf2f(hv.w), aw);
    }
  }
  float inn = in_norm[node];
  ushort4 r;
  r.x = f2bf(ax * inn); r.y = f2bf(ay * inn);
  r.z = f2bf(az * inn); r.w = f2bf(aw * inn);
  *(ushort4*)(aggr + (size_t)node * HID + lane * 4) = r;
}

// ---------- MFMA layer GEMM (128x128, K=256), optional fused FC ----------
template<int FC>
__global__ __launch_bounds__(512) void k_layer(u16* __restrict__ harr,
    const u16* __restrict__ aggr,
    const u16* __restrict__ WT, const float* __restrict__ bias,
    const float* __restrict__ in_norm,
    const u16* __restrict__ WfcT, const float* __restrict__ b_fc,
    float* __restrict__ out) {
  __shared__ char smem[135168];
  const int t = threadIdx.x;
  const int r0 = blockIdx.x * LBLK;

  #pragma unroll
  for (int i = 0; i < 4; ++i) {      // stage X h-half (32KB)
    int boff = i * 8192 + t * 16;
    int row = boff >> 8, col = boff & 255;
    uint4 v = *(const uint4*)(harr + (size_t)(r0 + row) * HID + (col >> 1));
    *(uint4*)(smem + row * 512 + (col ^ ((row & 7) << 4))) = v;
  }
  #pragma unroll
  for (int i = 0; i < 4; ++i) {      // stage X agg-half (32KB)
    int boff = i * 8192 + t * 16;
    int row = boff >> 8, col = boff & 255;
    uint4 v = *(const uint4*)(aggr + (size_t)(r0 + row) * HID + (col >> 1));
    *(uint4*)(smem + row * 512 + (256 + (col ^ ((row & 7) << 4)))) = v;
  }
  #pragma unroll
  for (int i = 0; i < 8; ++i) {      // stage W (64KB)
    int boff = i * 8192 + t * 16;
    int row = boff >> 9, col = boff & 511;
    uint4 v = *(const uint4*)(WT + (size_t)row * 256 + (col >> 1));
    *(uint4*)(smem + 65536 + row * 512 + (col ^ ((row & 7) << 4))) = v;
  }
  if (FC && t < 256) {               // stage WfcT (4KB)
    int row = t >> 4, col = (t & 15) * 16;
    uint4 v = *(const uint4*)(WfcT + (size_t)row * 128 + (col >> 1));
    *(uint4*)(smem + 131072 + row * 256 + (col ^ ((row & 7) << 4))) = v;
  }
  __syncthreads();

  const int lane = t & 63, w = t >> 6;
  const int l15 = lane & 15, lhi = lane >> 4;

  f32x4 acc[8];
  #pragma unroll
  for (int nf = 0; nf < 8; ++nf) acc[nf] = (f32x4){0.f, 0.f, 0.f, 0.f};

  const int arow = w * 16 + l15;
  const char* pa = smem + arow * 512;
  const int aswz = (arow & 7) << 4;
  #pragma unroll
  for (int ks = 0; ks < 8; ++ks) {
    int kb = ks * 64 + (lhi << 4);
    short8 a = *(const short8*)(pa + (kb ^ aswz));
    #pragma unroll
    for (int nf = 0; nf < 8; ++nf) {
      int brow = nf * 16 + l15;
      short8 bf = *(const short8*)(smem + 65536 + brow * 512 + (kb ^ ((brow & 7) << 4)));
      acc[nf] = __builtin_amdgcn_mfma_f32_16x16x32_bf16(a, bf, acc[nf], 0, 0, 0);
    }
  }

  float bcol[8];
  #pragma unroll
  for (int nf = 0; nf < 8; ++nf) bcol[nf] = bias[nf * 16 + l15];

  if (!FC) {
    #pragma unroll
    for (int r = 0; r < 4; ++r) {
      int grow = r0 + w * 16 + (lhi << 2) + r;
      if (grow < NN) {
        float inn = in_norm[grow];
        #pragma unroll
        for (int nf = 0; nf < 8; ++nf) {
          float v = acc[nf][r] + inn * bcol[nf];
          harr[(size_t)grow * HID + nf * 16 + l15] = f2bf(fmaxf(v, 0.f));
        }
      }
    }
  } else {
    __syncthreads();   // h2 overlays X rows: wait until all waves done reading X
    #pragma unroll
    for (int r = 0; r < 4; ++r) {
      int lrow = w * 16 + (lhi << 2) + r;
      int grow = r0 + lrow;
      float inn = (grow < NN) ? in_norm[grow] : 0.f;
      #pragma unroll
      for (int nf = 0; nf < 8; ++nf) {
        int col = nf * 16 + l15;
        float v = fmaxf(acc[nf][r] + inn * bcol[nf], 0.f);
        *(u16*)(smem + lrow * 256 + ((col * 2) ^ ((lrow & 7) << 4))) = f2bf(v);
      }
    }
    __syncthreads();
    f32x4 a2 = (f32x4){0.f, 0.f, 0.f, 0.f};
    const char* pa2 = smem + (w * 16 + l15) * 256;
    const int as2 = (l15 & 7) << 4;
    #pragma unroll
    for (int ks = 0; ks < 4; ++ks) {
      int kb = ks * 64 + (lhi << 4);
      short8 a = *(const short8*)(pa2 + (kb ^ as2));
      short8 bf = *(const short8*)(smem + 131072 + l15 * 256 + (kb ^ as2));
      a2 = __builtin_amdgcn_mfma_f32_16x16x32_bf16(a, bf, a2, 0, 0, 0);
    }
    if (l15 < OUT_F) {
      float bo = b_fc[l15];
      #pragma unroll
      for (int r = 0; r < 4; ++r) {
        int grow = r0 + w * 16 + (lhi << 2) + r;
        if (grow < NN) out[(size_t)grow * OUT_F + l15] = a2[r] + bo;
      }
    }
  }
}

extern "C" void kernel_launch(void* const* d_in, const int* in_sizes, int n_in,
                              void* d_out, int out_size, void* d_ws, size_t ws_size,
                              hipStream_t stream) {
  (void)in_sizes; (void)n_in; (void)out_size;
  const float* inputs  = (const float*)d_in[0];
  const int*   src     = (const int*)d_in[1];
  const int*   dst     = (const int*)d_in[2];
  const float* e_w     = (const float*)d_in[3];
  const float* W_emb   = (const float*)d_in[6];
  const float* b_emb   = (const float*)d_in[7];
  const float* W_self1 = (const float*)d_in[8];
  const float* W1      = (const float*)d_in[9];
  const float* b1      = (const float*)d_in[10];
  const float* W_self2 = (const float*)d_in[11];
  const float* W2      = (const float*)d_in[12];
  const float* b2      = (const float*)d_in[13];
  const float* W_fc    = (const float*)d_in[14];
  const float* b_fc    = (const float*)d_in[15];
  float* out = (float*)d_out;

  // layout (66.4 MB, < proven 72.2 MB) — round-10 layout:
  // [histgD 1M | totalsD 4K | estartD 4K | out_norm | in_norm | row_start
  //  | ebuf u64 EE 12.8M | harr 25.6M | aggr 25.6M | WTs]
  // whist (u32, 128*16384 = 8.4MB) overlays ebuf ONLY (consumed by k1's onorm
  // before k_passb writes ebuf; no harr conflict).
  u32* histgD      = (u32*)d_ws;
  u32* totalsD     = histgD + (size_t)PA_BLKS * 1024;
  u32* estartD     = totalsD + 1024;
  float* out_norm  = (float*)(estartD + 1024);
  float* in_norm   = out_norm + NN;
  int* row_start   = (int*)(in_norm + NN);
  u64* ebuf        = (u64*)(row_start + NN + 4);
  u16* harr        = (u16*)(ebuf + EE);
  u16* aggr        = harr + (size_t)NN * HID;
  u16* WT1         = aggr + (size_t)NN * HID;
  u16* WT2         = WT1 + 32768;
  u16* WfcT        = WT2 + 32768;
  u32* whist       = (u32*)ebuf;         // 8.4MB overlay inside ebuf (12.8MB)

  const size_t NEED = (size_t)PA_BLKS * 1024 * 4 + 2048 * 4 + (size_t)(3 * NN + 4) * 4
                      + (size_t)EE * 8 + (size_t)NN * HID * 4 + (2 * 32768 + 2048) * 2;
  if (ws_size < NEED) return;

  hipLaunchKernelGGL(k_odeg, dim3(OW_GRP * OW_CPY), dim3(256), 0, stream, src, whist);
  hipLaunchKernelGGL(k1, dim3(K1_GRID), dim3(256), 0, stream,
                     dst, histgD, inputs, W_emb, b_emb, harr,
                     W_self1, W1, W_self2, W2, W_fc, WT1, WT2, WfcT,
                     whist, out_norm);
  hipLaunchKernelGGL(k_scan1, dim3(NBKT), dim3(256), 0, stream, histgD, totalsD);
  hipLaunchKernelGGL(k_scan2, dim3(1), dim3(1024), 0, stream, totalsD, estartD);
  hipLaunchKernelGGL(k_passb, dim3(PA_BLKS), dim3(256), 0, stream,
                     src, dst, e_w, histgD, estartD, ebuf);
  hipLaunchKernelGGL(k_reorder, dim3(NBKT), dim3(256), 0, stream,
                     ebuf, estartD, row_start, in_norm);
  // layer 1
  hipLaunchKernelGGL(k_agg, dim3((NN + 7) / 8), dim3(256), 0, stream,
                     harr, row_start, in_norm, out_norm, ebuf, aggr);
  hipLaunchKernelGGL(k_layer<0>, dim3((NN + LBLK - 1) / LBLK), dim3(512), 0, stream,
                     harr, aggr, WT1, b1, in_norm, WfcT, b_fc, out);
  // layer 2 + fused FC
  hipLaunchKernelGGL(k_agg, dim3((NN + 7) / 8), dim3(256), 0, stream,
                     harr, row_start, in_norm, out_norm, ebuf, aggr);
  hipLaunchKernelGGL(k_layer<1>, dim3((NN + LBLK - 1) / LBLK), dim3(512), 0, stream,
                     harr, aggr, WT2, b2, in_norm, WfcT, b_fc, out);
}

// Round 15
// 352.231 us; speedup vs baseline: 1.3283x; 1.0580x over previous
//
#include <hip/hip_runtime.h>

#define NN 100000
#define EE 1600000
#define IN_F 24
#define HID 128
#define OUT_F 12
#define LBLK 128        // rows per layer-GEMM block

#define NBKT 782        // dst buckets of 128 nodes
#define PA_BLKS 256     // bucket-count / scatter blocks
#define PA_EPB 6250     // EE / PA_BLKS

#define OW_BITS 13
#define OWIN 8192       // out-deg window (16KB packed-u16 LDS)
#define OW_GRP 13       // ceil(NN/OWIN)
#define OW_CPY 48       // slices per window -> 624 blocks, whist 10.2MB < ebuf
#define OW_EPB 33334    // ceil(EE/OW_CPY)

#define RCAP 2560       // reorder LDS stage capacity (mean 2046, sigma 45 -> 11 sigma)

#define EMB_B 2048
#define PREP_B 264
#define ONORM_B 196     // ceil((NN/2)/256)
#define K1_GRID (PA_BLKS + EMB_B + PREP_B + ONORM_B)   // 2764

typedef unsigned char u8;
typedef unsigned short u16;
typedef unsigned int u32;
typedef unsigned long long u64;

using short8 = __attribute__((ext_vector_type(8))) short;
using f32x4  = __attribute__((ext_vector_type(4))) float;

__device__ __forceinline__ float bf2f(u16 h) {
  return __uint_as_float(((u32)h) << 16);
}
__device__ __forceinline__ u16 f2bf(float f) {
  u32 u = __float_as_uint(f);
  u32 r = (u + 0x7FFFu + ((u >> 16) & 1u)) >> 16;   // RNE
  return (u16)r;
}
__device__ __forceinline__ float inv_sqrt_cnt(int c) {
  if (c < 1) c = 1;
  return 1.0f / sqrtf((float)c);
}

// ---------- out-degree: windowed packed-u16 LDS histograms, 624 blocks ----------
__global__ __launch_bounds__(256) void k_odeg(const int* __restrict__ src,
                                              u32* __restrict__ whist) {
  __shared__ u32 hist[OWIN / 2];   // 16KB: u16 pair per u32
  int b = blockIdx.x, t = threadIdx.x;
  int g = b / OW_CPY, sb = b % OW_CPY;
  for (int i = t; i < OWIN / 2; i += 256) hist[i] = 0;
  __syncthreads();
  int e0 = sb * OW_EPB;
  int e1 = e0 + OW_EPB; if (e1 > EE) e1 = EE;
  for (int e = e0 + t; e < e1; e += 256) {
    int s = src[e];
    if ((s >> OW_BITS) == g) {
      int i = s & (OWIN - 1);
      atomicAdd(&hist[i >> 1], (i & 1) ? 0x10000u : 1u);
    }
  }
  __syncthreads();
  u32* out = whist + (size_t)b * (OWIN / 2);
  for (int i = t; i < OWIN / 2; i += 256) out[i] = hist[i];
}

// ---------- K1 sub-bodies ----------
__device__ __forceinline__ void emb_body(int eb, const float* __restrict__ inputs,
                                         const float* __restrict__ W_emb,
                                         const float* __restrict__ b_emb,
                                         u16* __restrict__ harr, float* smemW) {
  int t = threadIdx.x;
  float* Wls = smemW;
  float* bls = smemW + IN_F * HID;
  for (int i = t; i < IN_F * HID; i += 256) Wls[i] = W_emb[i];
  if (t < HID) bls[t] = b_emb[t];
  __syncthreads();
  int c = t & 127;
  int sub = t >> 7;
  for (int node = eb * 2 + sub; node < NN; node += EMB_B * 2) {
    const float* xr = inputs + (size_t)node * IN_F;
    float acc = bls[c];
    #pragma unroll
    for (int k = 0; k < IN_F; ++k) acc = fmaf(xr[k], Wls[k * HID + c], acc);
    harr[(size_t)node * HID + c] = f2bf(acc);
  }
}

__device__ __forceinline__ void prep_body(int pb,
    const float* __restrict__ Ws1, const float* __restrict__ W1m,
    const float* __restrict__ Ws2, const float* __restrict__ W2m,
    const float* __restrict__ Wfc,
    u16* __restrict__ WT1, u16* __restrict__ WT2, u16* __restrict__ WfcT) {
  int idx = pb * 256 + (int)threadIdx.x;
  if (idx < 65536) {
    int layer = idx >> 15;
    int rem = idx & 32767;
    int n = rem >> 8, k = rem & 255;
    const float* A = layer ? Ws2 : Ws1;
    const float* B = layer ? W2m : W1m;
    float v = (k < HID) ? A[(size_t)k * HID + n] : B[(size_t)(k - HID) * HID + n];
    (layer ? WT2 : WT1)[(size_t)n * 256 + k] = f2bf(v);
  } else if (idx < 65536 + 2048) {
    int j = idx - 65536;
    int n = j >> 7, k = j & 127;
    WfcT[(size_t)n * 128 + k] = f2bf(n < OUT_F ? Wfc[(size_t)k * OUT_F + n] : 0.f);
  }
}

__device__ __forceinline__ void onorm_body(int ob, const u32* __restrict__ whist,
                                           float* __restrict__ out_norm) {
  int i = ob * 256 + (int)threadIdx.x;   // packed node pair
  if (i >= NN / 2) return;
  int n0 = 2 * i;
  int g = n0 >> OW_BITS;
  int pi = (n0 & (OWIN - 1)) >> 1;
  const u32* base = whist + (size_t)g * OW_CPY * (OWIN / 2) + pi;
  u32 s = 0;
  #pragma unroll 8
  for (int c = 0; c < OW_CPY; ++c) s += base[(size_t)c * (OWIN / 2)];
  out_norm[n0]     = inv_sqrt_cnt((int)(s & 0xFFFFu));
  out_norm[n0 + 1] = inv_sqrt_cnt((int)(s >> 16));
}

// K1: fused [dst bucket-count | emb | weight prep | out-norm merge]
__global__ __launch_bounds__(256) void k1(
    const int* __restrict__ dst, u32* __restrict__ histgD,
    const float* __restrict__ inputs, const float* __restrict__ W_emb,
    const float* __restrict__ b_emb, u16* __restrict__ harr,
    const float* __restrict__ Ws1, const float* __restrict__ W1m,
    const float* __restrict__ Ws2, const float* __restrict__ W2m,
    const float* __restrict__ Wfc,
    u16* __restrict__ WT1, u16* __restrict__ WT2, u16* __restrict__ WfcT,
    const u32* __restrict__ whist, float* __restrict__ out_norm) {
  __shared__ __align__(16) char sm[13312];
  int b = blockIdx.x, t = threadIdx.x;
  if (b < PA_BLKS) {
    u32* histD = (u32*)sm;
    for (int i = t; i < 1024; i += 256) histD[i] = 0;
    __syncthreads();
    int e0 = b * PA_EPB;
    for (int e = e0 + t; e < e0 + PA_EPB; e += 256)
      atomicAdd(&histD[dst[e] >> 7], 1u);
    __syncthreads();
    for (int i = t; i < 1024; i += 256) histgD[(size_t)b * 1024 + i] = histD[i];
  } else if (b < PA_BLKS + EMB_B) {
    emb_body(b - PA_BLKS, inputs, W_emb, b_emb, harr, (float*)sm);
  } else if (b < PA_BLKS + EMB_B + PREP_B) {
    prep_body(b - PA_BLKS - EMB_B, Ws1, W1m, Ws2, W2m, Wfc, WT1, WT2, WfcT);
  } else {
    onorm_body(b - PA_BLKS - EMB_B - PREP_B, whist, out_norm);
  }
}

// scan1: per bucket k, exclusive scan over the 256 count blocks (in-place) + total
__global__ __launch_bounds__(256) void k_scan1(u32* __restrict__ histgD,
                                               u32* __restrict__ totalsD) {
  __shared__ u32 s[256];
  int k = blockIdx.x, t = threadIdx.x;
  u32 v = histgD[(size_t)t * 1024 + k];
  s[t] = v;
  __syncthreads();
  for (int off = 1; off < 256; off <<= 1) {
    u32 a = (t >= off) ? s[t - off] : 0;
    __syncthreads();
    s[t] += a;
    __syncthreads();
  }
  histgD[(size_t)t * 1024 + k] = s[t] - v;   // exclusive
  if (t == 255) totalsD[k] = s[255];
}

// scan2: exclusive scan over bucket totals -> estart[0..NBKT]
__global__ __launch_bounds__(1024) void k_scan2(const u32* __restrict__ totalsD,
                                                u32* __restrict__ estartD) {
  __shared__ u32 s[1024];
  int t = threadIdx.x;
  u32 v = (t < NBKT) ? totalsD[t] : 0;
  s[t] = v;
  __syncthreads();
  for (int off = 1; off < 1024; off <<= 1) {
    u32 a = (t >= off) ? s[t - off] : 0;
    __syncthreads();
    s[t] += a;
    __syncthreads();
  }
  if (t < NBKT) estartD[t] = s[t] - v;
  if (t == NBKT - 1) estartD[NBKT] = s[t];
}

// passB: scatter u64 edge records to bucket order via LDS cursors.
__global__ __launch_bounds__(256) void k_passb(
    const int* __restrict__ src, const int* __restrict__ dst,
    const float* __restrict__ e_w,
    const u32* __restrict__ histgD, const u32* __restrict__ estartD,
    u64* __restrict__ ebuf) {
  __shared__ u32 cur[1024];
  int pb = blockIdx.x, t = threadIdx.x;
  for (int i = t; i < 1024; i += 256)
    cur[i] = ((i < NBKT) ? estartD[i] : 0u) + histgD[(size_t)pb * 1024 + i];
  __syncthreads();
  int e0 = pb * PA_EPB;
  for (int e = e0 + t; e < e0 + PA_EPB; e += 256) {
    int s = src[e], d = dst[e];
    u32 hi = (u32)s | (((u32)(d & 127)) << 17);
    u64 rec = ((u64)hi << 32) | (u64)__float_as_uint(e_w[e]);
    u32 pos = atomicAdd(&cur[d >> 7], 1u);   // LDS atomic
    ebuf[pos] = rec;
  }
}

// reorder: within-bucket counting sort IN PLACE via LDS staging.
__global__ __launch_bounds__(256) void k_reorder(
    u64* __restrict__ ebuf, const u32* __restrict__ estart,
    int* __restrict__ row_start, float* __restrict__ in_norm) {
  __shared__ u64 stage[RCAP];
  __shared__ u32 cnt[128], pfx[128], cur[128];
  int k = blockIdx.x, t = threadIdx.x;
  if (t < 128) cnt[t] = 0;
  __syncthreads();
  int e0 = (int)estart[k], e1 = (int)estart[k + 1];
  int n = e1 - e0; if (n > RCAP) n = RCAP;   // 11-sigma impossible
  for (int i = t; i < n; i += 256) {
    u64 v = ebuf[e0 + i];
    stage[i] = v;
    atomicAdd(&cnt[(u32)(v >> 49) & 127], 1u);
  }
  __syncthreads();
  if (t < 128) pfx[t] = cnt[t];
  __syncthreads();
  for (int off = 1; off < 128; off <<= 1) {
    u32 v = (t < 128 && t >= off) ? pfx[t - off] : 0;
    __syncthreads();
    if (t < 128) pfx[t] += v;
    __syncthreads();
  }
  if (t < 128) {
    u32 start = (u32)e0 + pfx[t] - cnt[t];
    cur[t] = start;
    int node = k * 128 + t;
    if (node < NN) {
      row_start[node] = (int)start;
      in_norm[node] = inv_sqrt_cnt((int)cnt[t]);
    }
  }
  if (k == NBKT - 1 && t == 0) row_start[NN] = e1;
  __syncthreads();
  for (int i = t; i < n; i += 256) {
    u64 v = stage[i];
    u32 pos = atomicAdd(&cur[(u32)(v >> 49) & 127], 1u);
    ebuf[pos] = v;
  }
}

// agg (round-10 proven form): 4-deep MLP gather from compact harr.
__global__ __launch_bounds__(256) void k_agg(const u16* __restrict__ harr,
                                             const int* __restrict__ row_start,
                                             const float* __restrict__ in_norm,
                                             const float* __restrict__ out_norm,
                                             const u64* __restrict__ ebuf,
                                             u16* __restrict__ aggr) {
  int t = threadIdx.x;
  int node = blockIdx.x * 8 + (t >> 5);
  if (node >= NN) return;
  int lane = t & 31;
  int s0 = row_start[node], s1 = row_start[node + 1];
  float ax = 0.f, ay = 0.f, az = 0.f, aw = 0.f;
  for (int i0 = s0; i0 < s1; i0 += 32) {
    u32 pk2 = 0;
    if (i0 + lane < s1) {
      u64 rec = ebuf[i0 + lane];
      u32 sv = (u32)(rec >> 32) & 0x1FFFF;
      float w = __uint_as_float((u32)rec) * out_norm[sv];
      pk2 = (((u32)f2bf(w)) << 17) | sv;
    }
    int m = s1 - i0; if (m > 32) m = 32;
    int j = 0;
    for (; j + 4 <= m; j += 4) {
      u32 p0 = __shfl(pk2, j,     32);
      u32 p1 = __shfl(pk2, j + 1, 32);
      u32 p2 = __shfl(pk2, j + 2, 32);
      u32 p3 = __shfl(pk2, j + 3, 32);
      ushort4 h0 = *(const ushort4*)(harr + (size_t)(p0 & 0x1FFFF) * HID + lane * 4);
      ushort4 h1 = *(const ushort4*)(harr + (size_t)(p1 & 0x1FFFF) * HID + lane * 4);
      ushort4 h2 = *(const ushort4*)(harr + (size_t)(p2 & 0x1FFFF) * HID + lane * 4);
      ushort4 h3 = *(const ushort4*)(harr + (size_t)(p3 & 0x1FFFF) * HID + lane * 4);
      float w0 = bf2f((u16)(p0 >> 17));
      float w1 = bf2f((u16)(p1 >> 17));
      float w2 = bf2f((u16)(p2 >> 17));
      float w3 = bf2f((u16)(p3 >> 17));
      ax = fmaf(w0, bf2f(h0.x), ax); ay = fmaf(w0, bf2f(h0.y), ay);
      az = fmaf(w0, bf2f(h0.z), az); aw = fmaf(w0, bf2f(h0.w), aw);
      ax = fmaf(w1, bf2f(h1.x), ax); ay = fmaf(w1, bf2f(h1.y), ay);
      az = fmaf(w1, bf2f(h1.z), az); aw = fmaf(w1, bf2f(h1.w), aw);
      ax = fmaf(w2, bf2f(h2.x), ax); ay = fmaf(w2, bf2f(h2.y), ay);
      az = fmaf(w2, bf2f(h2.z), az); aw = fmaf(w2, bf2f(h2.w), aw);
      ax = fmaf(w3, bf2f(h3.x), ax); ay = fmaf(w3, bf2f(h3.y), ay);
      az = fmaf(w3, bf2f(h3.z), az); aw = fmaf(w3, bf2f(h3.w), aw);
    }
    for (; j < m; ++j) {
      u32 p = __shfl(pk2, j, 32);
      float w = bf2f((u16)(p >> 17));
      ushort4 hv = *(const ushort4*)(harr + (size_t)(p & 0x1FFFF) * HID + lane * 4);
      ax = fmaf(w, bf2f(hv.x), ax); ay = fmaf(w, bf2f(hv.y), ay);
      az = fmaf(w, bf2f(hv.z), az); aw = fmaf(w, bf2f(hv.w), aw);
    }
  }
  float inn = in_norm[node];
  ushort4 r;
  r.x = f2bf(ax * inn); r.y = f2bf(ay * inn);
  r.z = f2bf(az * inn); r.w = f2bf(aw * inn);
  *(ushort4*)(aggr + (size_t)node * HID + lane * 4) = r;
}

// ---------- MFMA layer GEMM (128x128, K=256), optional fused FC ----------
template<int FC>
__global__ __launch_bounds__(512) void k_layer(u16* __restrict__ harr,
    const u16* __restrict__ aggr,
    const u16* __restrict__ WT, const float* __restrict__ bias,
    const float* __restrict__ in_norm,
    const u16* __restrict__ WfcT, const float* __restrict__ b_fc,
    float* __restrict__ out) {
  __shared__ char smem[135168];
  const int t = threadIdx.x;
  const int r0 = blockIdx.x * LBLK;

  #pragma unroll
  for (int i = 0; i < 4; ++i) {      // stage X h-half (32KB)
    int boff = i * 8192 + t * 16;
    int row = boff >> 8, col = boff & 255;
    uint4 v = *(const uint4*)(harr + (size_t)(r0 + row) * HID + (col >> 1));
    *(uint4*)(smem + row * 512 + (col ^ ((row & 7) << 4))) = v;
  }
  #pragma unroll
  for (int i = 0; i < 4; ++i) {      // stage X agg-half (32KB)
    int boff = i * 8192 + t * 16;
    int row = boff >> 8, col = boff & 255;
    uint4 v = *(const uint4*)(aggr + (size_t)(r0 + row) * HID + (col >> 1));
    *(uint4*)(smem + row * 512 + (256 + (col ^ ((row & 7) << 4)))) = v;
  }
  #pragma unroll
  for (int i = 0; i < 8; ++i) {      // stage W (64KB)
    int boff = i * 8192 + t * 16;
    int row = boff >> 9, col = boff & 511;
    uint4 v = *(const uint4*)(WT + (size_t)row * 256 + (col >> 1));
    *(uint4*)(smem + 65536 + row * 512 + (col ^ ((row & 7) << 4))) = v;
  }
  if (FC && t < 256) {               // stage WfcT (4KB)
    int row = t >> 4, col = (t & 15) * 16;
    uint4 v = *(const uint4*)(WfcT + (size_t)row * 128 + (col >> 1));
    *(uint4*)(smem + 131072 + row * 256 + (col ^ ((row & 7) << 4))) = v;
  }
  __syncthreads();

  const int lane = t & 63, w = t >> 6;
  const int l15 = lane & 15, lhi = lane >> 4;

  f32x4 acc[8];
  #pragma unroll
  for (int nf = 0; nf < 8; ++nf) acc[nf] = (f32x4){0.f, 0.f, 0.f, 0.f};

  const int arow = w * 16 + l15;
  const char* pa = smem + arow * 512;
  const int aswz = (arow & 7) << 4;
  #pragma unroll
  for (int ks = 0; ks < 8; ++ks) {
    int kb = ks * 64 + (lhi << 4);
    short8 a = *(const short8*)(pa + (kb ^ aswz));
    #pragma unroll
    for (int nf = 0; nf < 8; ++nf) {
      int brow = nf * 16 + l15;
      short8 bf = *(const short8*)(smem + 65536 + brow * 512 + (kb ^ ((brow & 7) << 4)));
      acc[nf] = __builtin_amdgcn_mfma_f32_16x16x32_bf16(a, bf, acc[nf], 0, 0, 0);
    }
  }

  float bcol[8];
  #pragma unroll
  for (int nf = 0; nf < 8; ++nf) bcol[nf] = bias[nf * 16 + l15];

  if (!FC) {
    #pragma unroll
    for (int r = 0; r < 4; ++r) {
      int grow = r0 + w * 16 + (lhi << 2) + r;
      if (grow < NN) {
        float inn = in_norm[grow];
        #pragma unroll
        for (int nf = 0; nf < 8; ++nf) {
          float v = acc[nf][r] + inn * bcol[nf];
          harr[(size_t)grow * HID + nf * 16 + l15] = f2bf(fmaxf(v, 0.f));
        }
      }
    }
  } else {
    __syncthreads();   // h2 overlays X rows: wait until all waves done reading X
    #pragma unroll
    for (int r = 0; r < 4; ++r) {
      int lrow = w * 16 + (lhi << 2) + r;
      int grow = r0 + lrow;
      float inn = (grow < NN) ? in_norm[grow] : 0.f;
      #pragma unroll
      for (int nf = 0; nf < 8; ++nf) {
        int col = nf * 16 + l15;
        float v = fmaxf(acc[nf][r] + inn * bcol[nf], 0.f);
        *(u16*)(smem + lrow * 256 + ((col * 2) ^ ((lrow & 7) << 4))) = f2bf(v);
      }
    }
    __syncthreads();
    f32x4 a2 = (f32x4){0.f, 0.f, 0.f, 0.f};
    const char* pa2 = smem + (w * 16 + l15) * 256;
    const int as2 = (l15 & 7) << 4;
    #pragma unroll
    for (int ks = 0; ks < 4; ++ks) {
      int kb = ks * 64 + (lhi << 4);
      short8 a = *(const short8*)(pa2 + (kb ^ as2));
      short8 bf = *(const short8*)(smem + 131072 + l15 * 256 + (kb ^ as2));
      a2 = __builtin_amdgcn_mfma_f32_16x16x32_bf16(a, bf, a2, 0, 0, 0);
    }
    if (l15 < OUT_F) {
      float bo = b_fc[l15];
      #pragma unroll
      for (int r = 0; r < 4; ++r) {
        int grow = r0 + w * 16 + (lhi << 2) + r;
        if (grow < NN) out[(size_t)grow * OUT_F + l15] = a2[r] + bo;
      }
    }
  }
}

extern "C" void kernel_launch(void* const* d_in, const int* in_sizes, int n_in,
                              void* d_out, int out_size, void* d_ws, size_t ws_size,
                              hipStream_t stream) {
  (void)in_sizes; (void)n_in; (void)out_size;
  const float* inputs  = (const float*)d_in[0];
  const int*   src     = (const int*)d_in[1];
  const int*   dst     = (const int*)d_in[2];
  const float* e_w     = (const float*)d_in[3];
  const float* W_emb   = (const float*)d_in[6];
  const float* b_emb   = (const float*)d_in[7];
  const float* W_self1 = (const float*)d_in[8];
  const float* W1      = (const float*)d_in[9];
  const float* b1      = (const float*)d_in[10];
  const float* W_self2 = (const float*)d_in[11];
  const float* W2      = (const float*)d_in[12];
  const float* b2      = (const float*)d_in[13];
  const float* W_fc    = (const float*)d_in[14];
  const float* b_fc    = (const float*)d_in[15];
  float* out = (float*)d_out;

  // layout (66.4 MB, < proven 72.2 MB) — round-10 layout:
  // [histgD 1M | totalsD 4K | estartD 4K | out_norm | in_norm | row_start
  //  | ebuf u64 EE 12.8M | harr 25.6M | aggr 25.6M | WTs]
  // whist (u32, 624*4096 = 10.2MB) overlays ebuf ONLY (consumed by k1's onorm
  // before k_passb writes ebuf; no harr conflict).
  u32* histgD      = (u32*)d_ws;
  u32* totalsD     = histgD + (size_t)PA_BLKS * 1024;
  u32* estartD     = totalsD + 1024;
  float* out_norm  = (float*)(estartD + 1024);
  float* in_norm   = out_norm + NN;
  int* row_start   = (int*)(in_norm + NN);
  u64* ebuf        = (u64*)(row_start + NN + 4);
  u16* harr        = (u16*)(ebuf + EE);
  u16* aggr        = harr + (size_t)NN * HID;
  u16* WT1         = aggr + (size_t)NN * HID;
  u16* WT2         = WT1 + 32768;
  u16* WfcT        = WT2 + 32768;
  u32* whist       = (u32*)ebuf;         // 10.2MB overlay inside ebuf (12.8MB)

  const size_t NEED = (size_t)PA_BLKS * 1024 * 4 + 2048 * 4 + (size_t)(3 * NN + 4) * 4
                      + (size_t)EE * 8 + (size_t)NN * HID * 4 + (2 * 32768 + 2048) * 2;
  if (ws_size < NEED) return;

  hipLaunchKernelGGL(k_odeg, dim3(OW_GRP * OW_CPY), dim3(256), 0, stream, src, whist);
  hipLaunchKernelGGL(k1, dim3(K1_GRID), dim3(256), 0, stream,
                     dst, histgD, inputs, W_emb, b_emb, harr,
                     W_self1, W1, W_self2, W2, W_fc, WT1, WT2, WfcT,
                     whist, out_norm);
  hipLaunchKernelGGL(k_scan1, dim3(NBKT), dim3(256), 0, stream, histgD, totalsD);
  hipLaunchKernelGGL(k_scan2, dim3(1), dim3(1024), 0, stream, totalsD, estartD);
  hipLaunchKernelGGL(k_passb, dim3(PA_BLKS), dim3(256), 0, stream,
                     src, dst, e_w, histgD, estartD, ebuf);
  hipLaunchKernelGGL(k_reorder, dim3(NBKT), dim3(256), 0, stream,
                     ebuf, estartD, row_start, in_norm);
  // layer 1
  hipLaunchKernelGGL(k_agg, dim3((NN + 7) / 8), dim3(256), 0, stream,
                     harr, row_start, in_norm, out_norm, ebuf, aggr);
  hipLaunchKernelGGL(k_layer<0>, dim3((NN + LBLK - 1) / LBLK), dim3(512), 0, stream,
                     harr, aggr, WT1, b1, in_norm, WfcT, b_fc, out);
  // layer 2 + fused FC
  hipLaunchKernelGGL(k_agg, dim3((NN + 7) / 8), dim3(256), 0, stream,
                     harr, row_start, in_norm, out_norm, ebuf, aggr);
  hipLaunchKernelGGL(k_layer<1>, dim3((NN + LBLK - 1) / LBLK), dim3(512), 0, stream,
                     harr, aggr, WT2, b2, in_norm, WfcT, b_fc, out);
}

// Round 16
// 334.935 us; speedup vs baseline: 1.3968x; 1.0516x over previous
//
#include <hip/hip_runtime.h>

#define NN 100000
#define EE 1600000
#define IN_F 24
#define HID 128
#define OUT_F 12
#define LBLK 128        // rows per layer-GEMM block

#define NBKT 782        // dst buckets of 128 nodes
#define PA_BLKS 256     // bucket-count / scatter blocks
#define PA_EPB 6250     // EE / PA_BLKS

#define OW_BITS 13
#define OWIN 8192       // out-deg window (16KB packed-u16 LDS)
#define OW_GRP 13       // ceil(NN/OWIN)
#define OW_CPY 48       // slices per window -> 624 blocks, whist 10.2MB < ebuf
#define OW_EPB 33334    // ceil(EE/OW_CPY)

#define RCAP 2560       // reorder LDS stage capacity (mean 2046, sigma 45 -> 11 sigma)

#define EMB_B 2048
#define PREP_B 264
#define ONORM_B 196     // ceil((NN/2)/256)
#define K1_GRID (PA_BLKS + EMB_B + PREP_B + ONORM_B)   // 2764

typedef unsigned char u8;
typedef unsigned short u16;
typedef unsigned int u32;
typedef unsigned long long u64;

using short8 = __attribute__((ext_vector_type(8))) short;
using f32x4  = __attribute__((ext_vector_type(4))) float;

__device__ __forceinline__ float bf2f(u16 h) {
  return __uint_as_float(((u32)h) << 16);
}
__device__ __forceinline__ u16 f2bf(float f) {
  u32 u = __float_as_uint(f);
  u32 r = (u + 0x7FFFu + ((u >> 16) & 1u)) >> 16;   // RNE
  return (u16)r;
}
__device__ __forceinline__ float inv_sqrt_cnt(int c) {
  if (c < 1) c = 1;
  return 1.0f / sqrtf((float)c);
}

// ---------- out-degree: windowed packed-u16 LDS histograms, 624 blocks ----------
__global__ __launch_bounds__(256) void k_odeg(const int* __restrict__ src,
                                              u32* __restrict__ whist) {
  __shared__ u32 hist[OWIN / 2];   // 16KB: u16 pair per u32
  int b = blockIdx.x, t = threadIdx.x;
  int g = b / OW_CPY, sb = b % OW_CPY;
  for (int i = t; i < OWIN / 2; i += 256) hist[i] = 0;
  __syncthreads();
  int e0 = sb * OW_EPB;
  int e1 = e0 + OW_EPB; if (e1 > EE) e1 = EE;
  for (int e = e0 + t; e < e1; e += 256) {
    int s = src[e];
    if ((s >> OW_BITS) == g) {
      int i = s & (OWIN - 1);
      atomicAdd(&hist[i >> 1], (i & 1) ? 0x10000u : 1u);
    }
  }
  __syncthreads();
  u32* out = whist + (size_t)b * (OWIN / 2);
  for (int i = t; i < OWIN / 2; i += 256) out[i] = hist[i];
}

// ---------- K1 sub-bodies ----------
__device__ __forceinline__ void emb_body(int eb, const float* __restrict__ inputs,
                                         const float* __restrict__ W_emb,
                                         const float* __restrict__ b_emb,
                                         u16* __restrict__ harr, float* smemW) {
  int t = threadIdx.x;
  float* Wls = smemW;
  float* bls = smemW + IN_F * HID;
  for (int i = t; i < IN_F * HID; i += 256) Wls[i] = W_emb[i];
  if (t < HID) bls[t] = b_emb[t];
  __syncthreads();
  int c = t & 127;
  int sub = t >> 7;
  for (int node = eb * 2 + sub; node < NN; node += EMB_B * 2) {
    const float* xr = inputs + (size_t)node * IN_F;
    float acc = bls[c];
    #pragma unroll
    for (int k = 0; k < IN_F; ++k) acc = fmaf(xr[k], Wls[k * HID + c], acc);
    harr[(size_t)node * HID + c] = f2bf(acc);
  }
}

__device__ __forceinline__ void prep_body(int pb,
    const float* __restrict__ Ws1, const float* __restrict__ W1m,
    const float* __restrict__ Ws2, const float* __restrict__ W2m,
    const float* __restrict__ Wfc,
    u16* __restrict__ WT1, u16* __restrict__ WT2, u16* __restrict__ WfcT) {
  int idx = pb * 256 + (int)threadIdx.x;
  if (idx < 65536) {
    int layer = idx >> 15;
    int rem = idx & 32767;
    int n = rem >> 8, k = rem & 255;
    const float* A = layer ? Ws2 : Ws1;
    const float* B = layer ? W2m : W1m;
    float v = (k < HID) ? A[(size_t)k * HID + n] : B[(size_t)(k - HID) * HID + n];
    (layer ? WT2 : WT1)[(size_t)n * 256 + k] = f2bf(v);
  } else if (idx < 65536 + 2048) {
    int j = idx - 65536;
    int n = j >> 7, k = j & 127;
    WfcT[(size_t)n * 128 + k] = f2bf(n < OUT_F ? Wfc[(size_t)k * OUT_F + n] : 0.f);
  }
}

__device__ __forceinline__ void onorm_body(int ob, const u32* __restrict__ whist,
                                           float* __restrict__ out_norm) {
  int i = ob * 256 + (int)threadIdx.x;   // packed node pair
  if (i >= NN / 2) return;
  int n0 = 2 * i;
  int g = n0 >> OW_BITS;
  int pi = (n0 & (OWIN - 1)) >> 1;
  const u32* base = whist + (size_t)g * OW_CPY * (OWIN / 2) + pi;
  u32 s = 0;
  #pragma unroll 8
  for (int c = 0; c < OW_CPY; ++c) s += base[(size_t)c * (OWIN / 2)];
  out_norm[n0]     = inv_sqrt_cnt((int)(s & 0xFFFFu));
  out_norm[n0 + 1] = inv_sqrt_cnt((int)(s >> 16));
}

// K1: fused [dst bucket-count | emb | weight prep | out-norm merge]
__global__ __launch_bounds__(256) void k1(
    const int* __restrict__ dst, u32* __restrict__ histgD,
    const float* __restrict__ inputs, const float* __restrict__ W_emb,
    const float* __restrict__ b_emb, u16* __restrict__ harr,
    const float* __restrict__ Ws1, const float* __restrict__ W1m,
    const float* __restrict__ Ws2, const float* __restrict__ W2m,
    const float* __restrict__ Wfc,
    u16* __restrict__ WT1, u16* __restrict__ WT2, u16* __restrict__ WfcT,
    const u32* __restrict__ whist, float* __restrict__ out_norm) {
  __shared__ __align__(16) char sm[13312];
  int b = blockIdx.x, t = threadIdx.x;
  if (b < PA_BLKS) {
    u32* histD = (u32*)sm;
    for (int i = t; i < 1024; i += 256) histD[i] = 0;
    __syncthreads();
    int e0 = b * PA_EPB;
    for (int e = e0 + t; e < e0 + PA_EPB; e += 256)
      atomicAdd(&histD[dst[e] >> 7], 1u);
    __syncthreads();
    for (int i = t; i < 1024; i += 256) histgD[(size_t)b * 1024 + i] = histD[i];
  } else if (b < PA_BLKS + EMB_B) {
    emb_body(b - PA_BLKS, inputs, W_emb, b_emb, harr, (float*)sm);
  } else if (b < PA_BLKS + EMB_B + PREP_B) {
    prep_body(b - PA_BLKS - EMB_B, Ws1, W1m, Ws2, W2m, Wfc, WT1, WT2, WfcT);
  } else {
    onorm_body(b - PA_BLKS - EMB_B - PREP_B, whist, out_norm);
  }
}

// scan1: per bucket k, exclusive scan over the 256 count blocks (in-place) + total
__global__ __launch_bounds__(256) void k_scan1(u32* __restrict__ histgD,
                                               u32* __restrict__ totalsD) {
  __shared__ u32 s[256];
  int k = blockIdx.x, t = threadIdx.x;
  u32 v = histgD[(size_t)t * 1024 + k];
  s[t] = v;
  __syncthreads();
  for (int off = 1; off < 256; off <<= 1) {
    u32 a = (t >= off) ? s[t - off] : 0;
    __syncthreads();
    s[t] += a;
    __syncthreads();
  }
  histgD[(size_t)t * 1024 + k] = s[t] - v;   // exclusive
  if (t == 255) totalsD[k] = s[255];
}

// scan2: exclusive scan over bucket totals -> estart[0..NBKT]
__global__ __launch_bounds__(1024) void k_scan2(const u32* __restrict__ totalsD,
                                                u32* __restrict__ estartD) {
  __shared__ u32 s[1024];
  int t = threadIdx.x;
  u32 v = (t < NBKT) ? totalsD[t] : 0;
  s[t] = v;
  __syncthreads();
  for (int off = 1; off < 1024; off <<= 1) {
    u32 a = (t >= off) ? s[t - off] : 0;
    __syncthreads();
    s[t] += a;
    __syncthreads();
  }
  if (t < NBKT) estartD[t] = s[t] - v;
  if (t == NBKT - 1) estartD[NBKT] = s[t];
}

// passB: scatter u64 edge records to bucket order via LDS cursors.
__global__ __launch_bounds__(256) void k_passb(
    const int* __restrict__ src, const int* __restrict__ dst,
    const float* __restrict__ e_w,
    const u32* __restrict__ histgD, const u32* __restrict__ estartD,
    u64* __restrict__ ebuf) {
  __shared__ u32 cur[1024];
  int pb = blockIdx.x, t = threadIdx.x;
  for (int i = t; i < 1024; i += 256)
    cur[i] = ((i < NBKT) ? estartD[i] : 0u) + histgD[(size_t)pb * 1024 + i];
  __syncthreads();
  int e0 = pb * PA_EPB;
  for (int e = e0 + t; e < e0 + PA_EPB; e += 256) {
    int s = src[e], d = dst[e];
    u32 hi = (u32)s | (((u32)(d & 127)) << 17);
    u64 rec = ((u64)hi << 32) | (u64)__float_as_uint(e_w[e]);
    u32 pos = atomicAdd(&cur[d >> 7], 1u);   // LDS atomic
    ebuf[pos] = rec;
  }
}

// reorder: within-bucket counting sort IN PLACE via LDS staging.
// NEW (r16): folds w = e_w * out_norm[src] into the record's low 32 bits
// (packed (f2bf(w)<<17)|src) so k_agg skips the per-edge out_norm gather.
__global__ __launch_bounds__(256) void k_reorder(
    u64* __restrict__ ebuf, const u32* __restrict__ estart,
    const float* __restrict__ out_norm,
    int* __restrict__ row_start, float* __restrict__ in_norm) {
  __shared__ u64 stage[RCAP];
  __shared__ u32 cnt[128], pfx[128], cur[128];
  int k = blockIdx.x, t = threadIdx.x;
  if (t < 128) cnt[t] = 0;
  __syncthreads();
  int e0 = (int)estart[k], e1 = (int)estart[k + 1];
  int n = e1 - e0; if (n > RCAP) n = RCAP;   // 11-sigma impossible
  for (int i = t; i < n; i += 256) {
    u64 v = ebuf[e0 + i];
    stage[i] = v;
    atomicAdd(&cnt[(u32)(v >> 49) & 127], 1u);
  }
  __syncthreads();
  if (t < 128) pfx[t] = cnt[t];
  __syncthreads();
  for (int off = 1; off < 128; off <<= 1) {
    u32 v = (t < 128 && t >= off) ? pfx[t - off] : 0;
    __syncthreads();
    if (t < 128) pfx[t] += v;
    __syncthreads();
  }
  if (t < 128) {
    u32 start = (u32)e0 + pfx[t] - cnt[t];
    cur[t] = start;
    int node = k * 128 + t;
    if (node < NN) {
      row_start[node] = (int)start;
      in_norm[node] = inv_sqrt_cnt((int)cnt[t]);
    }
  }
  if (k == NBKT - 1 && t == 0) row_start[NN] = e1;
  __syncthreads();
  for (int i = t; i < n; i += 256) {
    u64 v = stage[i];
    u32 hi = (u32)(v >> 32);
    u32 sv = hi & 0x1FFFF;
    float w = __uint_as_float((u32)v) * out_norm[sv];
    u64 nv = ((u64)hi << 32) | (u64)((((u32)f2bf(w)) << 17) | sv);
    u32 pos = atomicAdd(&cur[(hi >> 17) & 127], 1u);
    ebuf[pos] = nv;
  }
}

// agg: 4-deep MLP gather from compact harr; records carry pre-folded weight.
__global__ __launch_bounds__(256) void k_agg(const u16* __restrict__ harr,
                                             const int* __restrict__ row_start,
                                             const float* __restrict__ in_norm,
                                             const u64* __restrict__ ebuf,
                                             u16* __restrict__ aggr) {
  int t = threadIdx.x;
  int node = blockIdx.x * 8 + (t >> 5);
  if (node >= NN) return;
  int lane = t & 31;
  int s0 = row_start[node], s1 = row_start[node + 1];
  float ax = 0.f, ay = 0.f, az = 0.f, aw = 0.f;
  for (int i0 = s0; i0 < s1; i0 += 32) {
    u32 pk2 = 0;
    if (i0 + lane < s1) pk2 = (u32)ebuf[i0 + lane];   // pre-folded (w<<17)|src
    int m = s1 - i0; if (m > 32) m = 32;
    int j = 0;
    for (; j + 4 <= m; j += 4) {
      u32 p0 = __shfl(pk2, j,     32);
      u32 p1 = __shfl(pk2, j + 1, 32);
      u32 p2 = __shfl(pk2, j + 2, 32);
      u32 p3 = __shfl(pk2, j + 3, 32);
      ushort4 h0 = *(const ushort4*)(harr + (size_t)(p0 & 0x1FFFF) * HID + lane * 4);
      ushort4 h1 = *(const ushort4*)(harr + (size_t)(p1 & 0x1FFFF) * HID + lane * 4);
      ushort4 h2 = *(const ushort4*)(harr + (size_t)(p2 & 0x1FFFF) * HID + lane * 4);
      ushort4 h3 = *(const ushort4*)(harr + (size_t)(p3 & 0x1FFFF) * HID + lane * 4);
      float w0 = bf2f((u16)(p0 >> 17));
      float w1 = bf2f((u16)(p1 >> 17));
      float w2 = bf2f((u16)(p2 >> 17));
      float w3 = bf2f((u16)(p3 >> 17));
      ax = fmaf(w0, bf2f(h0.x), ax); ay = fmaf(w0, bf2f(h0.y), ay);
      az = fmaf(w0, bf2f(h0.z), az); aw = fmaf(w0, bf2f(h0.w), aw);
      ax = fmaf(w1, bf2f(h1.x), ax); ay = fmaf(w1, bf2f(h1.y), ay);
      az = fmaf(w1, bf2f(h1.z), az); aw = fmaf(w1, bf2f(h1.w), aw);
      ax = fmaf(w2, bf2f(h2.x), ax); ay = fmaf(w2, bf2f(h2.y), ay);
      az = fmaf(w2, bf2f(h2.z), az); aw = fmaf(w2, bf2f(h2.w), aw);
      ax = fmaf(w3, bf2f(h3.x), ax); ay = fmaf(w3, bf2f(h3.y), ay);
      az = fmaf(w3, bf2f(h3.z), az); aw = fmaf(w3, bf2f(h3.w), aw);
    }
    for (; j < m; ++j) {
      u32 p = __shfl(pk2, j, 32);
      float w = bf2f((u16)(p >> 17));
      ushort4 hv = *(const ushort4*)(harr + (size_t)(p & 0x1FFFF) * HID + lane * 4);
      ax = fmaf(w, bf2f(hv.x), ax); ay = fmaf(w, bf2f(hv.y), ay);
      az = fmaf(w, bf2f(hv.z), az); aw = fmaf(w, bf2f(hv.w), aw);
    }
  }
  float inn = in_norm[node];
  ushort4 r;
  r.x = f2bf(ax * inn); r.y = f2bf(ay * inn);
  r.z = f2bf(az * inn); r.w = f2bf(aw * inn);
  *(ushort4*)(aggr + (size_t)node * HID + lane * 4) = r;
}

// ---------- MFMA layer GEMM (128x128, K=256), optional fused FC ----------
// r16: X is NOT staged (zero cross-wave reuse) — each lane preloads its 8
// A-fragments directly from global before the W barrier. LDS = W 64KB +
// WfcT 4KB = 68KB -> 2 blocks/CU. FC's h2 buffer overlays the dead W region.
template<int FC>
__global__ __launch_bounds__(512) void k_layer(u16* __restrict__ harr,
    const u16* __restrict__ aggr,
    const u16* __restrict__ WT, const float* __restrict__ bias,
    const float* __restrict__ in_norm,
    const u16* __restrict__ WfcT, const float* __restrict__ b_fc,
    float* __restrict__ out) {
  __shared__ char smem[69632];   // [W 64KB | WfcT 4KB]; h2s overlays W (FC)
  const int t = threadIdx.x;
  const int r0 = blockIdx.x * LBLK;

  #pragma unroll
  for (int i = 0; i < 8; ++i) {      // stage W (64KB) at smem+0
    int boff = i * 8192 + t * 16;
    int row = boff >> 9, col = boff & 511;
    uint4 v = *(const uint4*)(WT + (size_t)row * 256 + (col >> 1));
    *(uint4*)(smem + row * 512 + (col ^ ((row & 7) << 4))) = v;
  }
  if (FC && t < 256) {               // stage WfcT (4KB) at smem+65536
    int row = t >> 4, col = (t & 15) * 16;
    uint4 v = *(const uint4*)(WfcT + (size_t)row * 128 + (col >> 1));
    *(uint4*)(smem + 65536 + row * 256 + (col ^ ((row & 7) << 4))) = v;
  }

  const int lane = t & 63, w = t >> 6;
  const int l15 = lane & 15, lhi = lane >> 4;
  const int arow = w * 16 + l15;

  // direct global A-fragment preloads (overlap HBM latency with W staging);
  // tail-block OOB rows read into following ws regions — benign, never written.
  short8 af[8];
  {
    const u16* rh = harr + (size_t)(r0 + arow) * HID;
    const u16* ra = aggr + (size_t)(r0 + arow) * HID;
    #pragma unroll
    for (int ks = 0; ks < 8; ++ks) {
      int kb = ks * 64 + (lhi << 4);   // byte offset in the 512B logical X row
      const u16* p = (kb < 256) ? (rh + (kb >> 1)) : (ra + ((kb - 256) >> 1));
      af[ks] = *(const short8*)p;
    }
  }
  __syncthreads();

  f32x4 acc[8];
  #pragma unroll
  for (int nf = 0; nf < 8; ++nf) acc[nf] = (f32x4){0.f, 0.f, 0.f, 0.f};

  #pragma unroll
  for (int ks = 0; ks < 8; ++ks) {
    int kb = ks * 64 + (lhi << 4);
    #pragma unroll
    for (int nf = 0; nf < 8; ++nf) {
      int brow = nf * 16 + l15;
      short8 bf = *(const short8*)(smem + brow * 512 + (kb ^ ((brow & 7) << 4)));
      acc[nf] = __builtin_amdgcn_mfma_f32_16x16x32_bf16(af[ks], bf, acc[nf], 0, 0, 0);
    }
  }

  float bcol[8];
  #pragma unroll
  for (int nf = 0; nf < 8; ++nf) bcol[nf] = bias[nf * 16 + l15];

  if (!FC) {
    #pragma unroll
    for (int r = 0; r < 4; ++r) {
      int grow = r0 + w * 16 + (lhi << 2) + r;
      if (grow < NN) {
        float inn = in_norm[grow];
        #pragma unroll
        for (int nf = 0; nf < 8; ++nf) {
          float v = acc[nf][r] + inn * bcol[nf];
          harr[(size_t)grow * HID + nf * 16 + l15] = f2bf(fmaxf(v, 0.f));
        }
      }
    }
  } else {
    __syncthreads();   // h2 overlays W: wait until all waves done reading W
    #pragma unroll
    for (int r = 0; r < 4; ++r) {
      int lrow = w * 16 + (lhi << 2) + r;
      int grow = r0 + lrow;
      float inn = (grow < NN) ? in_norm[grow] : 0.f;
      #pragma unroll
      for (int nf = 0; nf < 8; ++nf) {
        int col = nf * 16 + l15;
        float v = fmaxf(acc[nf][r] + inn * bcol[nf], 0.f);
        *(u16*)(smem + lrow * 256 + ((col * 2) ^ ((lrow & 7) << 4))) = f2bf(v);
      }
    }
    __syncthreads();
    f32x4 a2 = (f32x4){0.f, 0.f, 0.f, 0.f};
    const char* pa2 = smem + (w * 16 + l15) * 256;
    const int as2 = (l15 & 7) << 4;
    #pragma unroll
    for (int ks = 0; ks < 4; ++ks) {
      int kb = ks * 64 + (lhi << 4);
      short8 a = *(const short8*)(pa2 + (kb ^ as2));
      short8 bf = *(const short8*)(smem + 65536 + l15 * 256 + (kb ^ as2));
      a2 = __builtin_amdgcn_mfma_f32_16x16x32_bf16(a, bf, a2, 0, 0, 0);
    }
    if (l15 < OUT_F) {
      float bo = b_fc[l15];
      #pragma unroll
      for (int r = 0; r < 4; ++r) {
        int grow = r0 + w * 16 + (lhi << 2) + r;
        if (grow < NN) out[(size_t)grow * OUT_F + l15] = a2[r] + bo;
      }
    }
  }
}

extern "C" void kernel_launch(void* const* d_in, const int* in_sizes, int n_in,
                              void* d_out, int out_size, void* d_ws, size_t ws_size,
                              hipStream_t stream) {
  (void)in_sizes; (void)n_in; (void)out_size;
  const float* inputs  = (const float*)d_in[0];
  const int*   src     = (const int*)d_in[1];
  const int*   dst     = (const int*)d_in[2];
  const float* e_w     = (const float*)d_in[3];
  const float* W_emb   = (const float*)d_in[6];
  const float* b_emb   = (const float*)d_in[7];
  const float* W_self1 = (const float*)d_in[8];
  const float* W1      = (const float*)d_in[9];
  const float* b1      = (const float*)d_in[10];
  const float* W_self2 = (const float*)d_in[11];
  const float* W2      = (const float*)d_in[12];
  const float* b2      = (const float*)d_in[13];
  const float* W_fc    = (const float*)d_in[14];
  const float* b_fc    = (const float*)d_in[15];
  float* out = (float*)d_out;

  // layout (66.4 MB, < proven 72.2 MB):
  // [histgD 1M | totalsD 4K | estartD 4K | out_norm | in_norm | row_start
  //  | ebuf u64 EE 12.8M | harr 25.6M | aggr 25.6M | WTs]
  // whist (u32, 624*4096 = 10.2MB) overlays ebuf ONLY (consumed by k1's onorm
  // before k_passb writes ebuf; no harr conflict).
  u32* histgD      = (u32*)d_ws;
  u32* totalsD     = histgD + (size_t)PA_BLKS * 1024;
  u32* estartD     = totalsD + 1024;
  float* out_norm  = (float*)(estartD + 1024);
  float* in_norm   = out_norm + NN;
  int* row_start   = (int*)(in_norm + NN);
  u64* ebuf        = (u64*)(row_start + NN + 4);
  u16* harr        = (u16*)(ebuf + EE);
  u16* aggr        = harr + (size_t)NN * HID;
  u16* WT1         = aggr + (size_t)NN * HID;
  u16* WT2         = WT1 + 32768;
  u16* WfcT        = WT2 + 32768;
  u32* whist       = (u32*)ebuf;         // 10.2MB overlay inside ebuf (12.8MB)

  const size_t NEED = (size_t)PA_BLKS * 1024 * 4 + 2048 * 4 + (size_t)(3 * NN + 4) * 4
                      + (size_t)EE * 8 + (size_t)NN * HID * 4 + (2 * 32768 + 2048) * 2;
  if (ws_size < NEED) return;

  hipLaunchKernelGGL(k_odeg, dim3(OW_GRP * OW_CPY), dim3(256), 0, stream, src, whist);
  hipLaunchKernelGGL(k1, dim3(K1_GRID), dim3(256), 0, stream,
                     dst, histgD, inputs, W_emb, b_emb, harr,
                     W_self1, W1, W_self2, W2, W_fc, WT1, WT2, WfcT,
                     whist, out_norm);
  hipLaunchKernelGGL(k_scan1, dim3(NBKT), dim3(256), 0, stream, histgD, totalsD);
  hipLaunchKernelGGL(k_scan2, dim3(1), dim3(1024), 0, stream, totalsD, estartD);
  hipLaunchKernelGGL(k_passb, dim3(PA_BLKS), dim3(256), 0, stream,
                     src, dst, e_w, histgD, estartD, ebuf);
  hipLaunchKernelGGL(k_reorder, dim3(NBKT), dim3(256), 0, stream,
                     ebuf, estartD, out_norm, row_start, in_norm);
  // layer 1
  hipLaunchKernelGGL(k_agg, dim3((NN + 7) / 8), dim3(256), 0, stream,
                     harr, row_start, in_norm, ebuf, aggr);
  hipLaunchKernelGGL(k_layer<0>, dim3((NN + LBLK - 1) / LBLK), dim3(512), 0, stream,
                     harr, aggr, WT1, b1, in_norm, WfcT, b_fc, out);
  // layer 2 + fused FC
  hipLaunchKernelGGL(k_agg, dim3((NN + 7) / 8), dim3(256), 0, stream,
                     harr, row_start, in_norm, ebuf, aggr);
  hipLaunchKernelGGL(k_layer<1>, dim3((NN + LBLK - 1) / LBLK), dim3(512), 0, stream,
                     harr, aggr, WT2, b2, in_norm, WfcT, b_fc, out);
}